// Round 3
// baseline (2682.761 us; speedup 1.0000x reference)
//
#include <hip/hip_runtime.h>
#include <cstdint>

// Problem constants
#define BB 64
#define TT 1024
#define DD 256
#define HH 128
#define G4 512   // 4*H
#define NTAG 3

typedef __attribute__((ext_vector_type(8))) short bf16x8;
typedef __attribute__((ext_vector_type(4))) float f32x4;

__device__ __forceinline__ unsigned short f2bf(float f) {
    uint32_t u = __builtin_bit_cast(uint32_t, f);
    uint32_t r = (u + 0x7FFFu + ((u >> 16) & 1u)) >> 16;
    return (unsigned short)r;
}
__device__ __forceinline__ float bf2f(unsigned short s) {
    uint32_t u = ((uint32_t)s) << 16;
    return __builtin_bit_cast(float, u);
}
// raw HW transcendentals: v_exp_f32 / v_rcp_f32
__device__ __forceinline__ float sigm(float x) {
    return __builtin_amdgcn_rcpf(1.f + __builtin_amdgcn_exp2f(x * -1.44269504f));
}
__device__ __forceinline__ float tanh_f(float x) {
    // tanh(x) = 1 - 2/(1+e^{2x})
    return 1.f - 2.f * __builtin_amdgcn_rcpf(1.f + __builtin_amdgcn_exp2f(x * 2.88539008f));
}

// ---------------- fp32 -> bf16 conversion (vectorized x4) ----------------
__global__ void cvt4_kernel(const float* __restrict__ in, unsigned short* __restrict__ out, int n4) {
    int idx = blockIdx.x * blockDim.x + threadIdx.x;
    if (idx < n4) {
        float4 v = ((const float4*)in)[idx];
        ushort4 o;
        o.x = f2bf(v.x); o.y = f2bf(v.y); o.z = f2bf(v.z); o.w = f2bf(v.w);
        ((ushort4*)out)[idx] = o;
    }
}

// ---------------- input-projection GEMM: G = A @ W^T + b_ih + b_hh ----------------
// A: [65536, 256] bf16 row-major. W: [512, 256] bf16 row-major (N,K). G: [65536,512] bf16.
// grid (1024, 4, 2): x = 64-row M block, y = 128-col N strip, z = direction.
__global__ __launch_bounds__(256) void gemm_ih(
    const unsigned short* __restrict__ A,
    const unsigned short* __restrict__ W0, const unsigned short* __restrict__ W1,
    const float* __restrict__ bih0, const float* __restrict__ bhh0,
    const float* __restrict__ bih1, const float* __restrict__ bhh1,
    unsigned short* __restrict__ G0, unsigned short* __restrict__ G1)
{
    const int dir = blockIdx.z;
    const unsigned short* W = dir ? W1 : W0;
    const float* bih = dir ? bih1 : bih0;
    const float* bhh = dir ? bhh1 : bhh0;
    unsigned short* G = dir ? G1 : G0;

    const int wave = threadIdx.x >> 6;
    const int lane = threadIdx.x & 63;
    const int m16 = lane & 15;
    const int quad = lane >> 4;

    const int rowA = blockIdx.x * 64 + wave * 16 + m16;
    const int n0 = blockIdx.y * 128;

    // preload 8 A fragments (K = 8 x 32)
    bf16x8 afrag[8];
    const uint4* Abase = (const uint4*)(A + (size_t)rowA * DD + quad * 8);
#pragma unroll
    for (int kk = 0; kk < 8; kk++) {
        uint4 u = Abase[kk * 2]; // kk*32 ushorts = kk*2 uint4
        afrag[kk] = __builtin_bit_cast(bf16x8, u);
    }

#pragma unroll
    for (int nt = 0; nt < 8; nt++) {
        const int n = n0 + nt * 16 + m16;
        f32x4 acc = {0.f, 0.f, 0.f, 0.f};
        const uint4* Wbase = (const uint4*)(W + (size_t)n * DD + quad * 8);
#pragma unroll
        for (int kk = 0; kk < 8; kk++) {
            uint4 u = Wbase[kk * 2];
            bf16x8 bfrag = __builtin_bit_cast(bf16x8, u);
            acc = __builtin_amdgcn_mfma_f32_16x16x32_bf16(afrag[kk], bfrag, acc, 0, 0, 0);
        }
        const float bias = bih[n] + bhh[n];
        const int outRowBase = blockIdx.x * 64 + wave * 16 + quad * 4;
#pragma unroll
        for (int r = 0; r < 4; r++) {
            G[(size_t)(outRowBase + r) * G4 + n] = f2bf(acc[r] + bias);
        }
    }
}

// ---------------- MFMA LSTM recurrent scan, M=1, one barrier/step ----------------
// grid (64, 2): x = batch, y = direction. 512 threads = 8 waves.
// Wave wv owns hcols [16wv,16wv+16) for ALL 4 gates (N-tiles at n = 128p + 16wv).
// Gates stay in MFMA acc registers; lane (n16,quad==0) holds i,f,g,o for its hcol.
// h double-buffered in LDS (128 bf16); only n16==0 lanes read it as the A fragment.
__global__ __launch_bounds__(512, 2) void lstm_scan_mfma(
    const unsigned short* __restrict__ Gf, const unsigned short* __restrict__ Gr,
    const float* __restrict__ whh_f, const float* __restrict__ whh_r,
    unsigned short* __restrict__ out)
{
    const int b = blockIdx.x;
    const int dir = blockIdx.y;
    const unsigned short* G = dir ? Gr : Gf;
    const float* W = dir ? whh_r : whh_f;

    const int tid = threadIdx.x;
    const int wv = tid >> 6;
    const int lane = tid & 63;
    const int n16 = lane & 15;
    const int quad = lane >> 4;

    __shared__ __align__(16) unsigned short h_lds[2][HH];

    // preload b-fragments: tile p covers n = 128*p + wv*16 + n16; B[k][n] = w_hh[n][k]
    bf16x8 bfrag[4][4];
#pragma unroll
    for (int p = 0; p < 4; p++) {
        const int n = 128 * p + wv * 16 + n16;
        const float* Wr = W + (size_t)n * HH + quad * 8;
#pragma unroll
        for (int kc = 0; kc < 4; kc++) {
            float4 v0 = ((const float4*)(Wr + kc * 32))[0];
            float4 v1 = ((const float4*)(Wr + kc * 32))[1];
            bf16x8 f;
            f[0] = (short)f2bf(v0.x); f[1] = (short)f2bf(v0.y);
            f[2] = (short)f2bf(v0.z); f[3] = (short)f2bf(v0.w);
            f[4] = (short)f2bf(v1.x); f[5] = (short)f2bf(v1.y);
            f[6] = (short)f2bf(v1.z); f[7] = (short)f2bf(v1.w);
            bfrag[p][kc] = f;
        }
    }

    if (tid < HH) h_lds[0][tid] = 0;

    const bool dense = (quad == 0);
    const int hcol = wv * 16 + n16;
    float c = 0.f;

    // prefetch G for step 0 (dense lanes)
    float gpre[4] = {0.f, 0.f, 0.f, 0.f};
    if (dense) {
        const int t0 = dir ? (TT - 1) : 0;
        const unsigned short* gp = G + ((size_t)b * TT + t0) * G4 + hcol;
#pragma unroll
        for (int p = 0; p < 4; p++) gpre[p] = bf2f(gp[128 * p]);
    }
    __syncthreads();

    for (int s = 0; s < TT; s++) {
        const int t = dir ? (TT - 1 - s) : s;
        const int buf = s & 1;

        // prefetch next step's gate preacts (hidden behind MFMA + dense)
        float gnext[4] = {0.f, 0.f, 0.f, 0.f};
        if (dense && s + 1 < TT) {
            const int tn = dir ? (TT - 2 - s) : (s + 1);
            const unsigned short* gp = G + ((size_t)b * TT + tn) * G4 + hcol;
#pragma unroll
            for (int p = 0; p < 4; p++) gnext[p] = bf2f(gp[128 * p]);
        }

        // A fragment: only row 0 (lanes n16==0) carries h; rows 1..15 are zero
        bf16x8 afrag[4];
#pragma unroll
        for (int kc = 0; kc < 4; kc++) {
            uint4 u = {0u, 0u, 0u, 0u};
            if (n16 == 0) u = *(const uint4*)&h_lds[buf][kc * 32 + quad * 8];
            afrag[kc] = __builtin_bit_cast(bf16x8, u);
        }

        f32x4 acc[4];
#pragma unroll
        for (int p = 0; p < 4; p++) {
            f32x4 a = {0.f, 0.f, 0.f, 0.f};
#pragma unroll
            for (int kc = 0; kc < 4; kc++)
                a = __builtin_amdgcn_mfma_f32_16x16x32_bf16(afrag[kc], bfrag[p][kc], a, 0, 0, 0);
            acc[p] = a;
        }

        if (dense) {
            const float gi = acc[0][0] + gpre[0];
            const float gf = acc[1][0] + gpre[1];
            const float gg = acc[2][0] + gpre[2];
            const float go = acc[3][0] + gpre[3];
            const float ig = sigm(gi);
            const float fg = sigm(gf);
            const float gt = tanh_f(gg);
            const float og = sigm(go);
            c = fg * c + ig * gt;
            const float h = og * tanh_f(c);
            const unsigned short hb = f2bf(h);
            h_lds[buf ^ 1][hcol] = hb;
            out[((size_t)b * TT + t) * (2 * HH) + dir * HH + hcol] = hb;
        }
#pragma unroll
        for (int p = 0; p < 4; p++) gpre[p] = gnext[p];
        __syncthreads();
    }
}

// ---------------- emissions: out1 [65536,256] bf16 @ fc_w^T [3,256] + fc_b ----------------
__global__ __launch_bounds__(256) void emis_kernel(
    const unsigned short* __restrict__ out1,
    const float* __restrict__ fcw, const float* __restrict__ fcb,
    float* __restrict__ dout)
{
    __shared__ float wsm[NTAG * 256];
    for (int i = threadIdx.x; i < NTAG * 256; i += 256) wsm[i] = fcw[i];
    __syncthreads();

    const int bt = blockIdx.x * 256 + threadIdx.x;
    float a0 = fcb[0], a1 = fcb[1], a2 = fcb[2];
    const uint4* row = (const uint4*)(out1 + (size_t)bt * 256);
#pragma unroll 4
    for (int k8 = 0; k8 < 32; k8++) {
        uint4 u = row[k8];
        const int kb = k8 * 8;
        uint32_t p[4] = {u.x, u.y, u.z, u.w};
#pragma unroll
        for (int e = 0; e < 4; e++) {
            float flo = __builtin_bit_cast(float, p[e] << 16);
            float fhi = __builtin_bit_cast(float, p[e] & 0xFFFF0000u);
            const int k = kb + 2 * e;
            a0 = fmaf(flo, wsm[0 * 256 + k], a0);
            a1 = fmaf(flo, wsm[1 * 256 + k], a1);
            a2 = fmaf(flo, wsm[2 * 256 + k], a2);
            a0 = fmaf(fhi, wsm[0 * 256 + k + 1], a0);
            a1 = fmaf(fhi, wsm[1 * 256 + k + 1], a1);
            a2 = fmaf(fhi, wsm[2 * 256 + k + 1], a2);
        }
    }
    dout[1 + (size_t)bt * 3 + 0] = a0;
    dout[1 + (size_t)bt * 3 + 1] = a1;
    dout[1 + (size_t)bt * 3 + 2] = a2;
}

// ---------------- CRF NLL ----------------
__device__ __forceinline__ float sel3(int i, float a, float b, float c) {
    return i == 0 ? a : (i == 1 ? b : c);
}
__device__ __forceinline__ float lse3(float a, float b, float c) {
    float m = fmaxf(a, fmaxf(b, c));
    float s = exp2f((a - m) * 1.44269504f) + exp2f((b - m) * 1.44269504f) + exp2f((c - m) * 1.44269504f);
    return m + log2f(s) * 0.69314718f;
}

__global__ void crf_kernel(const int* __restrict__ tags,
                           const float* __restrict__ start, const float* __restrict__ end,
                           const float* __restrict__ trans, float* __restrict__ dout)
{
    const int b = threadIdx.x; // 64 threads, one wave
    float tr[3][3];
#pragma unroll
    for (int i = 0; i < 3; i++)
#pragma unroll
        for (int jj = 0; jj < 3; jj++) tr[i][jj] = trans[i * 3 + jj];
    const float s0 = start[0], s1 = start[1], s2 = start[2];
    const float e0c = end[0], e1c = end[1], e2c = end[2];

    const float* em = dout + 1 + (size_t)b * TT * 3;
    const int* tg = tags + (size_t)b * TT;

    int tprev = tg[0];
    float a0 = s0 + em[0], a1 = s1 + em[1], a2 = s2 + em[2];
    float num = sel3(tprev, s0, s1, s2) + sel3(tprev, em[0], em[1], em[2]);

    for (int t = 1; t < TT; t++) {
        const float e0 = em[t * 3 + 0], e1 = em[t * 3 + 1], e2 = em[t * 3 + 2];
        const int tt = tg[t];
        const float ee = sel3(tt, e0, e1, e2);
        const float trv = sel3(tprev,
                               sel3(tt, tr[0][0], tr[0][1], tr[0][2]),
                               sel3(tt, tr[1][0], tr[1][1], tr[1][2]),
                               sel3(tt, tr[2][0], tr[2][1], tr[2][2]));
        num += ee + trv;
        tprev = tt;
        const float n0 = lse3(a0 + tr[0][0], a1 + tr[1][0], a2 + tr[2][0]) + e0;
        const float n1 = lse3(a0 + tr[0][1], a1 + tr[1][1], a2 + tr[2][1]) + e1;
        const float n2 = lse3(a0 + tr[0][2], a1 + tr[1][2], a2 + tr[2][2]) + e2;
        a0 = n0; a1 = n1; a2 = n2;
    }
    num += sel3(tprev, e0c, e1c, e2c);
    const float logZ = lse3(a0 + e0c, a1 + e1c, a2 + e2c);
    float val = logZ - num; // per-batch contribution to loss

#pragma unroll
    for (int off = 32; off > 0; off >>= 1) val += __shfl_down(val, off, 64);
    if (b == 0) dout[0] = val / (float)BB;
}

// ---------------- launch ----------------
extern "C" void kernel_launch(void* const* d_in, const int* in_sizes, int n_in,
                              void* d_out, int out_size, void* d_ws, size_t ws_size,
                              hipStream_t stream) {
    const float* x        = (const float*)d_in[0];
    const int*   tags     = (const int*)d_in[1];
    const float* w_ih_l0  = (const float*)d_in[2];
    const float* w_hh_l0  = (const float*)d_in[3];
    const float* b_ih_l0  = (const float*)d_in[4];
    const float* b_hh_l0  = (const float*)d_in[5];
    const float* w_ih_l0r = (const float*)d_in[6];
    const float* w_hh_l0r = (const float*)d_in[7];
    const float* b_ih_l0r = (const float*)d_in[8];
    const float* b_hh_l0r = (const float*)d_in[9];
    const float* w_ih_l1  = (const float*)d_in[10];
    const float* w_hh_l1  = (const float*)d_in[11];
    const float* b_ih_l1  = (const float*)d_in[12];
    const float* b_hh_l1  = (const float*)d_in[13];
    const float* w_ih_l1r = (const float*)d_in[14];
    const float* w_hh_l1r = (const float*)d_in[15];
    const float* b_ih_l1r = (const float*)d_in[16];
    const float* b_hh_l1r = (const float*)d_in[17];
    const float* fc_w     = (const float*)d_in[18];
    const float* fc_b     = (const float*)d_in[19];
    const float* crf_start= (const float*)d_in[20];
    const float* crf_end  = (const float*)d_in[21];
    const float* crf_trans= (const float*)d_in[22];
    float* dout = (float*)d_out;

    uint8_t* ws = (uint8_t*)d_ws;
    // workspace layout (bytes)
    unsigned short* xb   = (unsigned short*)(ws + 0);          // 33.5 MB, reused as out1 later
    unsigned short* out1 = xb;
    unsigned short* out0 = (unsigned short*)(ws + 33554432);   // 33.5 MB
    unsigned short* Gf   = (unsigned short*)(ws + 67108864);   // 67 MB
    unsigned short* Gr   = (unsigned short*)(ws + 134217728);  // 67 MB
    unsigned short* wb0  = (unsigned short*)(ws + 201326592);  // 4 x 256 KB
    unsigned short* wb0r = wb0 + 131072;
    unsigned short* wb1  = wb0 + 262144;
    unsigned short* wb1r = wb0 + 393216;

    // 1. convert x and the 4 w_ih matrices to bf16
    cvt4_kernel<<<dim3((16777216 / 4 + 255) / 256), dim3(256), 0, stream>>>(x, xb, 16777216 / 4);
    cvt4_kernel<<<dim3(128), dim3(256), 0, stream>>>(w_ih_l0,  wb0,  131072 / 4);
    cvt4_kernel<<<dim3(128), dim3(256), 0, stream>>>(w_ih_l0r, wb0r, 131072 / 4);
    cvt4_kernel<<<dim3(128), dim3(256), 0, stream>>>(w_ih_l1,  wb1,  131072 / 4);
    cvt4_kernel<<<dim3(128), dim3(256), 0, stream>>>(w_ih_l1r, wb1r, 131072 / 4);

    // 2. layer 0: input projection + MFMA scan
    gemm_ih<<<dim3(1024, 4, 2), dim3(256), 0, stream>>>(
        xb, wb0, wb0r, b_ih_l0, b_hh_l0, b_ih_l0r, b_hh_l0r, Gf, Gr);
    lstm_scan_mfma<<<dim3(64, 2), dim3(512), 0, stream>>>(Gf, Gr, w_hh_l0, w_hh_l0r, out0);

    // 3. layer 1: input projection (reusing G buffers) + MFMA scan
    gemm_ih<<<dim3(1024, 4, 2), dim3(256), 0, stream>>>(
        out0, wb1, wb1r, b_ih_l1, b_hh_l1, b_ih_l1r, b_hh_l1r, Gf, Gr);
    lstm_scan_mfma<<<dim3(64, 2), dim3(512), 0, stream>>>(Gf, Gr, w_hh_l1, w_hh_l1r, out1);

    // 4. emissions
    emis_kernel<<<dim3(256), dim3(256), 0, stream>>>(out1, fc_w, fc_b, dout);

    // 5. CRF NLL -> dout[0]
    crf_kernel<<<dim3(1), dim3(64), 0, stream>>>(tags, crf_start, crf_end, crf_trans, dout);
}

// Round 4
// 1773.476 us; speedup vs baseline: 1.5127x; 1.5127x over previous
//
#include <hip/hip_runtime.h>
#include <cstdint>

// Problem constants
#define BB 64
#define TT 1024
#define DD 256
#define HH 128
#define G4 512   // 4*H
#define NTAG 3

typedef __attribute__((ext_vector_type(8))) short bf16x8;
typedef __attribute__((ext_vector_type(4))) float f32x4;

__device__ __forceinline__ unsigned short f2bf(float f) {
    uint32_t u = __builtin_bit_cast(uint32_t, f);
    uint32_t r = (u + 0x7FFFu + ((u >> 16) & 1u)) >> 16;
    return (unsigned short)r;
}
__device__ __forceinline__ float bf2f(unsigned short s) {
    uint32_t u = ((uint32_t)s) << 16;
    return __builtin_bit_cast(float, u);
}
// raw HW transcendentals: v_exp_f32 / v_rcp_f32
__device__ __forceinline__ float sigm(float x) {
    return __builtin_amdgcn_rcpf(1.f + __builtin_amdgcn_exp2f(x * -1.44269504f));
}
__device__ __forceinline__ float tanh_f(float x) {
    // tanh(x) = 1 - 2/(1+e^{2x})
    return 1.f - 2.f * __builtin_amdgcn_rcpf(1.f + __builtin_amdgcn_exp2f(x * 2.88539008f));
}

// ---------------- fp32 -> bf16 conversion (vectorized x4) ----------------
__global__ void cvt4_kernel(const float* __restrict__ in, unsigned short* __restrict__ out, int n4) {
    int idx = blockIdx.x * blockDim.x + threadIdx.x;
    if (idx < n4) {
        float4 v = ((const float4*)in)[idx];
        ushort4 o;
        o.x = f2bf(v.x); o.y = f2bf(v.y); o.z = f2bf(v.z); o.w = f2bf(v.w);
        ((ushort4*)out)[idx] = o;
    }
}

// ---------------- input-projection GEMM: G = A @ W^T + b_ih + b_hh ----------------
// A: [65536, 256] bf16 row-major. W: [512, 256] bf16 row-major (N,K). G: [65536,512] bf16.
// grid (1024, 4, 2): x = 64-row M block, y = 128-col N strip, z = direction.
__global__ __launch_bounds__(256) void gemm_ih(
    const unsigned short* __restrict__ A,
    const unsigned short* __restrict__ W0, const unsigned short* __restrict__ W1,
    const float* __restrict__ bih0, const float* __restrict__ bhh0,
    const float* __restrict__ bih1, const float* __restrict__ bhh1,
    unsigned short* __restrict__ G0, unsigned short* __restrict__ G1)
{
    const int dir = blockIdx.z;
    const unsigned short* W = dir ? W1 : W0;
    const float* bih = dir ? bih1 : bih0;
    const float* bhh = dir ? bhh1 : bhh0;
    unsigned short* G = dir ? G1 : G0;

    const int wave = threadIdx.x >> 6;
    const int lane = threadIdx.x & 63;
    const int m16 = lane & 15;
    const int quad = lane >> 4;

    const int rowA = blockIdx.x * 64 + wave * 16 + m16;
    const int n0 = blockIdx.y * 128;

    // preload 8 A fragments (K = 8 x 32)
    bf16x8 afrag[8];
    const uint4* Abase = (const uint4*)(A + (size_t)rowA * DD + quad * 8);
#pragma unroll
    for (int kk = 0; kk < 8; kk++) {
        uint4 u = Abase[kk * 2]; // kk*32 ushorts = kk*2 uint4
        afrag[kk] = __builtin_bit_cast(bf16x8, u);
    }

#pragma unroll
    for (int nt = 0; nt < 8; nt++) {
        const int n = n0 + nt * 16 + m16;
        f32x4 acc = {0.f, 0.f, 0.f, 0.f};
        const uint4* Wbase = (const uint4*)(W + (size_t)n * DD + quad * 8);
#pragma unroll
        for (int kk = 0; kk < 8; kk++) {
            uint4 u = Wbase[kk * 2];
            bf16x8 bfrag = __builtin_bit_cast(bf16x8, u);
            acc = __builtin_amdgcn_mfma_f32_16x16x32_bf16(afrag[kk], bfrag, acc, 0, 0, 0);
        }
        const float bias = bih[n] + bhh[n];
        const int outRowBase = blockIdx.x * 64 + wave * 16 + quad * 4;
#pragma unroll
        for (int r = 0; r < 4; r++) {
            G[(size_t)(outRowBase + r) * G4 + n] = f2bf(acc[r] + bias);
        }
    }
}

// ---------------- MFMA LSTM recurrent scan, M=1, one barrier/step, depth-4 G prefetch ----------------
// grid (64, 2): x = batch, y = direction. 512 threads = 8 waves.
// Wave wv owns hcols [16wv,16wv+16) for ALL 4 gates (N-tiles at n = 128p + 16wv).
// Gates stay in MFMA acc registers; lane (n16,quad==0) holds i,f,g,o for its hcol.
// h double-buffered in LDS (128 bf16); only n16==0 lanes read it as the A fragment.
// G preacts prefetched 4 steps ahead (static register slots via 4-unrolled loop).
__global__ __launch_bounds__(512, 2) void lstm_scan_mfma(
    const unsigned short* __restrict__ Gf, const unsigned short* __restrict__ Gr,
    const float* __restrict__ whh_f, const float* __restrict__ whh_r,
    unsigned short* __restrict__ out)
{
    const int b = blockIdx.x;
    const int dir = blockIdx.y;
    const unsigned short* G = dir ? Gr : Gf;
    const float* W = dir ? whh_r : whh_f;

    const int tid = threadIdx.x;
    const int wv = tid >> 6;
    const int lane = tid & 63;
    const int n16 = lane & 15;
    const int quad = lane >> 4;

    __shared__ __align__(16) unsigned short h_lds[2][HH];

    // preload b-fragments: tile p covers n = 128*p + wv*16 + n16; B[k][n] = w_hh[n][k]
    bf16x8 bfrag[4][4];
#pragma unroll
    for (int p = 0; p < 4; p++) {
        const int n = 128 * p + wv * 16 + n16;
        const float* Wr = W + (size_t)n * HH + quad * 8;
#pragma unroll
        for (int kc = 0; kc < 4; kc++) {
            float4 v0 = ((const float4*)(Wr + kc * 32))[0];
            float4 v1 = ((const float4*)(Wr + kc * 32))[1];
            bf16x8 f;
            f[0] = (short)f2bf(v0.x); f[1] = (short)f2bf(v0.y);
            f[2] = (short)f2bf(v0.z); f[3] = (short)f2bf(v0.w);
            f[4] = (short)f2bf(v1.x); f[5] = (short)f2bf(v1.y);
            f[6] = (short)f2bf(v1.z); f[7] = (short)f2bf(v1.w);
            bfrag[p][kc] = f;
        }
    }

    if (tid < HH) h_lds[0][tid] = 0;

    const bool dense = (quad == 0);
    const int hcol = wv * 16 + n16;
    float c = 0.f;

    // per-lane G base (all lanes compute/load; quads duplicate the same cache lines)
    const unsigned short* gb = G + (size_t)b * TT * G4 + hcol;

    // depth-4 prefetch slots: gq[d][p] holds step (sb+d)'s gate-p preact
    float gq[4][4];
#pragma unroll
    for (int d = 0; d < 4; d++) {
        const int t = dir ? (TT - 1 - d) : d;
        const unsigned short* gp = gb + (size_t)t * G4;
#pragma unroll
        for (int p = 0; p < 4; p++) gq[d][p] = bf2f(gp[128 * p]);
    }
    __syncthreads();

    for (int sb = 0; sb < TT; sb += 4) {
#pragma unroll
        for (int d = 0; d < 4; d++) {
            const int s = sb + d;
            const int t = dir ? (TT - 1 - s) : s;
            const int buf = s & 1;

            // A fragment: only row 0 (lanes n16==0) carries h; rows 1..15 are zero
            bf16x8 afrag[4];
#pragma unroll
            for (int kc = 0; kc < 4; kc++) {
                uint4 u = {0u, 0u, 0u, 0u};
                if (n16 == 0) u = *(const uint4*)&h_lds[buf][kc * 32 + quad * 8];
                afrag[kc] = __builtin_bit_cast(bf16x8, u);
            }

            f32x4 acc[4];
#pragma unroll
            for (int p = 0; p < 4; p++) {
                f32x4 a = {0.f, 0.f, 0.f, 0.f};
#pragma unroll
                for (int kc = 0; kc < 4; kc++)
                    a = __builtin_amdgcn_mfma_f32_16x16x32_bf16(afrag[kc], bfrag[p][kc], a, 0, 0, 0);
                acc[p] = a;
            }

            if (dense) {
                const float gi = acc[0][0] + gq[d][0];
                const float gf = acc[1][0] + gq[d][1];
                const float gg = acc[2][0] + gq[d][2];
                const float go = acc[3][0] + gq[d][3];
                const float ig = sigm(gi);
                const float fg = sigm(gf);
                const float gt = tanh_f(gg);
                const float og = sigm(go);
                c = fg * c + ig * gt;
                const float h = og * tanh_f(c);
                const unsigned short hb = f2bf(h);
                h_lds[buf ^ 1][hcol] = hb;
                out[((size_t)b * TT + t) * (2 * HH) + dir * HH + hcol] = hb;
            }

            // refill slot d with step s+4 (consumed 4 steps later; load stays in flight)
            {
                int sn = s + 4;
                int tn = dir ? (TT - 1 - sn) : sn;
                tn = tn < 0 ? 0 : (tn > TT - 1 ? TT - 1 : tn);
                const unsigned short* gp = gb + (size_t)tn * G4;
#pragma unroll
                for (int p = 0; p < 4; p++) gq[d][p] = bf2f(gp[128 * p]);
            }
            __syncthreads();
        }
    }
}

// ---------------- emissions: out1 [65536,256] bf16 @ fc_w^T [3,256] + fc_b ----------------
__global__ __launch_bounds__(256) void emis_kernel(
    const unsigned short* __restrict__ out1,
    const float* __restrict__ fcw, const float* __restrict__ fcb,
    float* __restrict__ dout)
{
    if (blockIdx.x == 0 && threadIdx.x == 0) dout[0] = 0.f; // init for CRF atomics

    __shared__ float wsm[NTAG * 256];
    for (int i = threadIdx.x; i < NTAG * 256; i += 256) wsm[i] = fcw[i];
    __syncthreads();

    const int bt = blockIdx.x * 256 + threadIdx.x;
    float a0 = fcb[0], a1 = fcb[1], a2 = fcb[2];
    const uint4* row = (const uint4*)(out1 + (size_t)bt * 256);
#pragma unroll 4
    for (int k8 = 0; k8 < 32; k8++) {
        uint4 u = row[k8];
        const int kb = k8 * 8;
        uint32_t p[4] = {u.x, u.y, u.z, u.w};
#pragma unroll
        for (int e = 0; e < 4; e++) {
            float flo = __builtin_bit_cast(float, p[e] << 16);
            float fhi = __builtin_bit_cast(float, p[e] & 0xFFFF0000u);
            const int k = kb + 2 * e;
            a0 = fmaf(flo, wsm[0 * 256 + k], a0);
            a1 = fmaf(flo, wsm[1 * 256 + k], a1);
            a2 = fmaf(flo, wsm[2 * 256 + k], a2);
            a0 = fmaf(fhi, wsm[0 * 256 + k + 1], a0);
            a1 = fmaf(fhi, wsm[1 * 256 + k + 1], a1);
            a2 = fmaf(fhi, wsm[2 * 256 + k + 1], a2);
        }
    }
    dout[1 + (size_t)bt * 3 + 0] = a0;
    dout[1 + (size_t)bt * 3 + 1] = a1;
    dout[1 + (size_t)bt * 3 + 2] = a2;
}

// ---------------- CRF NLL: log-semiring parallel scan ----------------
__device__ __forceinline__ float sel3(int i, float a, float b, float c) {
    return i == 0 ? a : (i == 1 ? b : c);
}
__device__ __forceinline__ float lse3(float a, float b, float c) {
    float m = fmaxf(a, fmaxf(b, c));
    float s = exp2f((a - m) * 1.44269504f) + exp2f((b - m) * 1.44269504f) + exp2f((c - m) * 1.44269504f);
    return m + log2f(s) * 0.69314718f;
}

// grid (64): one block (one wave) per batch. Thread th folds transition matrices
// t in [1+16th, 1+16th+16); 6-level shuffle tree combines; numerator by shuffle-add.
__global__ __launch_bounds__(64) void crf_kernel(
    const int* __restrict__ tags,
    const float* __restrict__ start, const float* __restrict__ end,
    const float* __restrict__ trans, float* __restrict__ dout)
{
    const int b = blockIdx.x;
    const int th = threadIdx.x;
    const float* em = dout + 1 + (size_t)b * TT * 3;
    const int* tg = tags + (size_t)b * TT;

    float tr[3][3];
#pragma unroll
    for (int i = 0; i < 3; i++)
#pragma unroll
        for (int j = 0; j < 3; j++) tr[i][j] = trans[i * 3 + j];

    // log-semiring identity
    float P[3][3];
#pragma unroll
    for (int i = 0; i < 3; i++)
#pragma unroll
        for (int j = 0; j < 3; j++) P[i][j] = (i == j) ? 0.f : -1e30f;

    const int t0 = 1 + 16 * th;
    float numpart = 0.f;
    int tprev = tg[t0 - 1];

    for (int d = 0; d < 16; d++) {
        const int t = t0 + d;
        if (t < TT) {
            const float e0 = em[3 * t + 0], e1 = em[3 * t + 1], e2 = em[3 * t + 2];
            // P = P (*) M_t, where M_t[k][j] = tr[k][j] + e_j
            float N[3][3];
#pragma unroll
            for (int i = 0; i < 3; i++) {
                N[i][0] = lse3(P[i][0] + tr[0][0], P[i][1] + tr[1][0], P[i][2] + tr[2][0]) + e0;
                N[i][1] = lse3(P[i][0] + tr[0][1], P[i][1] + tr[1][1], P[i][2] + tr[2][1]) + e1;
                N[i][2] = lse3(P[i][0] + tr[0][2], P[i][1] + tr[1][2], P[i][2] + tr[2][2]) + e2;
            }
#pragma unroll
            for (int i = 0; i < 3; i++)
#pragma unroll
                for (int j = 0; j < 3; j++) P[i][j] = N[i][j];
            const int tc = tg[t];
            numpart += sel3(tc, e0, e1, e2) + sel3(tprev,
                         sel3(tc, tr[0][0], tr[0][1], tr[0][2]),
                         sel3(tc, tr[1][0], tr[1][1], tr[1][2]),
                         sel3(tc, tr[2][0], tr[2][1], tr[2][2]));
            tprev = tc;
        }
    }

    // tree combine: chunk order is by lane index; left = lower lane
#pragma unroll
    for (int off = 1; off < 64; off <<= 1) {
        float Q[3][3];
#pragma unroll
        for (int i = 0; i < 3; i++)
#pragma unroll
            for (int j = 0; j < 3; j++) Q[i][j] = __shfl_xor(P[i][j], off, 64);
        const bool hi = (th & off) != 0;
        float L[3][3], R[3][3];
#pragma unroll
        for (int i = 0; i < 3; i++)
#pragma unroll
            for (int j = 0; j < 3; j++) {
                L[i][j] = hi ? Q[i][j] : P[i][j];
                R[i][j] = hi ? P[i][j] : Q[i][j];
            }
#pragma unroll
        for (int i = 0; i < 3; i++)
#pragma unroll
            for (int j = 0; j < 3; j++)
                P[i][j] = lse3(L[i][0] + R[0][j], L[i][1] + R[1][j], L[i][2] + R[2][j]);
        numpart += __shfl_xor(numpart, off, 64);
    }

    if (th == 0) {
        const int tg0 = tg[0], tgL = tg[TT - 1];
        const float a0 = start[0] + em[0], a1 = start[1] + em[1], a2 = start[2] + em[2];
        const float f0 = lse3(a0 + P[0][0], a1 + P[1][0], a2 + P[2][0]);
        const float f1 = lse3(a0 + P[0][1], a1 + P[1][1], a2 + P[2][1]);
        const float f2 = lse3(a0 + P[0][2], a1 + P[1][2], a2 + P[2][2]);
        const float logZ = lse3(f0 + end[0], f1 + end[1], f2 + end[2]);
        const float num = sel3(tg0, start[0], start[1], start[2]) +
                          sel3(tg0, em[0], em[1], em[2]) + numpart +
                          sel3(tgL, end[0], end[1], end[2]);
        atomicAdd(&dout[0], (logZ - num) * (1.0f / (float)BB));
    }
}

// ---------------- launch ----------------
extern "C" void kernel_launch(void* const* d_in, const int* in_sizes, int n_in,
                              void* d_out, int out_size, void* d_ws, size_t ws_size,
                              hipStream_t stream) {
    const float* x        = (const float*)d_in[0];
    const int*   tags     = (const int*)d_in[1];
    const float* w_ih_l0  = (const float*)d_in[2];
    const float* w_hh_l0  = (const float*)d_in[3];
    const float* b_ih_l0  = (const float*)d_in[4];
    const float* b_hh_l0  = (const float*)d_in[5];
    const float* w_ih_l0r = (const float*)d_in[6];
    const float* w_hh_l0r = (const float*)d_in[7];
    const float* b_ih_l0r = (const float*)d_in[8];
    const float* b_hh_l0r = (const float*)d_in[9];
    const float* w_ih_l1  = (const float*)d_in[10];
    const float* w_hh_l1  = (const float*)d_in[11];
    const float* b_ih_l1  = (const float*)d_in[12];
    const float* b_hh_l1  = (const float*)d_in[13];
    const float* w_ih_l1r = (const float*)d_in[14];
    const float* w_hh_l1r = (const float*)d_in[15];
    const float* b_ih_l1r = (const float*)d_in[16];
    const float* b_hh_l1r = (const float*)d_in[17];
    const float* fc_w     = (const float*)d_in[18];
    const float* fc_b     = (const float*)d_in[19];
    const float* crf_start= (const float*)d_in[20];
    const float* crf_end  = (const float*)d_in[21];
    const float* crf_trans= (const float*)d_in[22];
    float* dout = (float*)d_out;

    uint8_t* ws = (uint8_t*)d_ws;
    // workspace layout (bytes)
    unsigned short* xb   = (unsigned short*)(ws + 0);          // 33.5 MB, reused as out1 later
    unsigned short* out1 = xb;
    unsigned short* out0 = (unsigned short*)(ws + 33554432);   // 33.5 MB
    unsigned short* Gf   = (unsigned short*)(ws + 67108864);   // 67 MB
    unsigned short* Gr   = (unsigned short*)(ws + 134217728);  // 67 MB
    unsigned short* wb0  = (unsigned short*)(ws + 201326592);  // 4 x 256 KB
    unsigned short* wb0r = wb0 + 131072;
    unsigned short* wb1  = wb0 + 262144;
    unsigned short* wb1r = wb0 + 393216;

    // 1. convert x and the 4 w_ih matrices to bf16
    cvt4_kernel<<<dim3((16777216 / 4 + 255) / 256), dim3(256), 0, stream>>>(x, xb, 16777216 / 4);
    cvt4_kernel<<<dim3(128), dim3(256), 0, stream>>>(w_ih_l0,  wb0,  131072 / 4);
    cvt4_kernel<<<dim3(128), dim3(256), 0, stream>>>(w_ih_l0r, wb0r, 131072 / 4);
    cvt4_kernel<<<dim3(128), dim3(256), 0, stream>>>(w_ih_l1,  wb1,  131072 / 4);
    cvt4_kernel<<<dim3(128), dim3(256), 0, stream>>>(w_ih_l1r, wb1r, 131072 / 4);

    // 2. layer 0: input projection + MFMA scan
    gemm_ih<<<dim3(1024, 4, 2), dim3(256), 0, stream>>>(
        xb, wb0, wb0r, b_ih_l0, b_hh_l0, b_ih_l0r, b_hh_l0r, Gf, Gr);
    lstm_scan_mfma<<<dim3(64, 2), dim3(512), 0, stream>>>(Gf, Gr, w_hh_l0, w_hh_l0r, out0);

    // 3. layer 1: input projection (reusing G buffers) + MFMA scan
    gemm_ih<<<dim3(1024, 4, 2), dim3(256), 0, stream>>>(
        out0, wb1, wb1r, b_ih_l1, b_hh_l1, b_ih_l1r, b_hh_l1r, Gf, Gr);
    lstm_scan_mfma<<<dim3(64, 2), dim3(512), 0, stream>>>(Gf, Gr, w_hh_l1, w_hh_l1r, out1);

    // 4. emissions (also zeroes dout[0] for the CRF atomics)
    emis_kernel<<<dim3(256), dim3(256), 0, stream>>>(out1, fc_w, fc_b, dout);

    // 5. CRF NLL -> dout[0] (parallel scan, one block per batch)
    crf_kernel<<<dim3(64), dim3(64), 0, stream>>>(tags, crf_start, crf_end, crf_trans, dout);
}

// Round 5
// 1622.403 us; speedup vs baseline: 1.6536x; 1.0931x over previous
//
#include <hip/hip_runtime.h>
#include <cstdint>

// Problem constants
#define BB 64
#define TT 1024
#define DD 256
#define HH 128
#define G4 512   // 4*H
#define NTAG 3

typedef __attribute__((ext_vector_type(8))) short bf16x8;
typedef __attribute__((ext_vector_type(4))) float f32x4;

__device__ __forceinline__ unsigned short f2bf(float f) {
    uint32_t u = __builtin_bit_cast(uint32_t, f);
    uint32_t r = (u + 0x7FFFu + ((u >> 16) & 1u)) >> 16;
    return (unsigned short)r;
}
__device__ __forceinline__ float bf2f(unsigned short s) {
    uint32_t u = ((uint32_t)s) << 16;
    return __builtin_bit_cast(float, u);
}
// raw HW transcendentals: v_exp_f32 / v_rcp_f32
__device__ __forceinline__ float sigm(float x) {
    return __builtin_amdgcn_rcpf(1.f + __builtin_amdgcn_exp2f(x * -1.44269504f));
}
__device__ __forceinline__ float tanh_f(float x) {
    // tanh(x) = 1 - 2/(1+e^{2x})
    return 1.f - 2.f * __builtin_amdgcn_rcpf(1.f + __builtin_amdgcn_exp2f(x * 2.88539008f));
}

// LDS-only barrier: s_waitcnt vmcnt(63) expcnt(7) lgkmcnt(0) + s_barrier.
// Crucially does NOT drain the vmem FIFO (global loads/stores stay in flight),
// unlike __syncthreads() which emits vmcnt(0) before s_barrier.
__device__ __forceinline__ void block_sync_lds() {
    __builtin_amdgcn_s_waitcnt(0xC07F);
    __builtin_amdgcn_s_barrier();
}

// ---------------- fp32 -> bf16 conversion (vectorized x4) ----------------
__global__ void cvt4_kernel(const float* __restrict__ in, unsigned short* __restrict__ out, int n4) {
    int idx = blockIdx.x * blockDim.x + threadIdx.x;
    if (idx < n4) {
        float4 v = ((const float4*)in)[idx];
        ushort4 o;
        o.x = f2bf(v.x); o.y = f2bf(v.y); o.z = f2bf(v.z); o.w = f2bf(v.w);
        ((ushort4*)out)[idx] = o;
    }
}

// ---------------- input-projection GEMM: G = A @ W^T + b_ih + b_hh ----------------
// A: [65536, 256] bf16 row-major. W: [512, 256] bf16 row-major (N,K).
// G layout: [row][hcol*4 + gate]  (gate-interleaved so the scan loads 4 gates as one 8B read).
// grid (1024, 4, 2): x = 64-row M block, y = 32-hcol strip (all 4 gates), z = direction.
__global__ __launch_bounds__(256) void gemm_ih(
    const unsigned short* __restrict__ A,
    const unsigned short* __restrict__ W0, const unsigned short* __restrict__ W1,
    const float* __restrict__ bih0, const float* __restrict__ bhh0,
    const float* __restrict__ bih1, const float* __restrict__ bhh1,
    unsigned short* __restrict__ G0, unsigned short* __restrict__ G1)
{
    const int dir = blockIdx.z;
    const unsigned short* W = dir ? W1 : W0;
    const float* bih = dir ? bih1 : bih0;
    const float* bhh = dir ? bhh1 : bhh0;
    unsigned short* G = dir ? G1 : G0;

    const int wave = threadIdx.x >> 6;
    const int lane = threadIdx.x & 63;
    const int m16 = lane & 15;
    const int quad = lane >> 4;

    const int rowA = blockIdx.x * 64 + wave * 16 + m16;
    const int hcol0 = blockIdx.y * 32;

    // preload 8 A fragments (K = 8 x 32)
    bf16x8 afrag[8];
    const uint4* Abase = (const uint4*)(A + (size_t)rowA * DD + quad * 8);
#pragma unroll
    for (int kk = 0; kk < 8; kk++) {
        uint4 u = Abase[kk * 2]; // kk*32 ushorts = kk*2 uint4
        afrag[kk] = __builtin_bit_cast(bf16x8, u);
    }

#pragma unroll
    for (int p = 0; p < 8; p++) {
        const int g = p & 3;       // gate
        const int j = p >> 2;      // 16-col half of the 32-hcol strip
        const int n = g * 128 + hcol0 + j * 16 + m16;
        f32x4 acc = {0.f, 0.f, 0.f, 0.f};
        const uint4* Wbase = (const uint4*)(W + (size_t)n * DD + quad * 8);
#pragma unroll
        for (int kk = 0; kk < 8; kk++) {
            uint4 u = Wbase[kk * 2];
            bf16x8 bfrag = __builtin_bit_cast(bf16x8, u);
            acc = __builtin_amdgcn_mfma_f32_16x16x32_bf16(afrag[kk], bfrag, acc, 0, 0, 0);
        }
        const float bias = bih[n] + bhh[n];
        const int outRowBase = blockIdx.x * 64 + wave * 16 + quad * 4;
        const int col = ((n & 127) << 2) + g;   // hcol*4 + gate
#pragma unroll
        for (int r = 0; r < 4; r++) {
            G[(size_t)(outRowBase + r) * G4 + col] = f2bf(acc[r] + bias);
        }
    }
}

// ---------------- MFMA LSTM recurrent scan ----------------
// grid (64, 2): x = batch, y = direction. 512 threads = 8 waves.
// Wave wv owns hcols [16wv,16wv+16) for ALL 4 gates (N-tiles at n = 128p + 16wv).
// Gates stay in MFMA acc registers; lane (n16, quad==0) holds i,f,g,o for its hcol.
// h double-buffered in LDS (128 bf16), read via same-address broadcast by all lanes
// (A rows 0..15 all equal h -> C rows all equal; row 0 consumed).
// G preacts (gate-interleaved layout) prefetched 4 steps ahead, one 8B load/lane/step.
// Raw LDS-only barrier keeps G loads + out stores in flight across steps.
__global__ __launch_bounds__(512, 2) void lstm_scan_mfma(
    const unsigned short* __restrict__ Gf, const unsigned short* __restrict__ Gr,
    const float* __restrict__ whh_f, const float* __restrict__ whh_r,
    unsigned short* __restrict__ out)
{
    const int b = blockIdx.x;
    const int dir = blockIdx.y;
    const unsigned short* G = dir ? Gr : Gf;
    const float* W = dir ? whh_r : whh_f;

    const int tid = threadIdx.x;
    const int wv = tid >> 6;
    const int lane = tid & 63;
    const int n16 = lane & 15;
    const int quad = lane >> 4;

    __shared__ __align__(16) unsigned short h_lds[2][HH];

    // preload b-fragments: tile p covers n = 128*p + wv*16 + n16; B[k][n] = w_hh[n][k]
    bf16x8 bfrag[4][4];
#pragma unroll
    for (int p = 0; p < 4; p++) {
        const int n = 128 * p + wv * 16 + n16;
        const float* Wr = W + (size_t)n * HH + quad * 8;
#pragma unroll
        for (int kc = 0; kc < 4; kc++) {
            float4 v0 = ((const float4*)(Wr + kc * 32))[0];
            float4 v1 = ((const float4*)(Wr + kc * 32))[1];
            bf16x8 f;
            f[0] = (short)f2bf(v0.x); f[1] = (short)f2bf(v0.y);
            f[2] = (short)f2bf(v0.z); f[3] = (short)f2bf(v0.w);
            f[4] = (short)f2bf(v1.x); f[5] = (short)f2bf(v1.y);
            f[6] = (short)f2bf(v1.z); f[7] = (short)f2bf(v1.w);
            bfrag[p][kc] = f;
        }
    }

    if (tid < HH) h_lds[0][tid] = 0;

    const bool dense = (quad == 0);
    const int hcol = wv * 16 + n16;
    float c = 0.f;

    // per-lane G base: 4 contiguous gate preacts for this hcol (quads duplicate -> same lines)
    const unsigned short* gb = G + (size_t)b * TT * G4 + hcol * 4;

    // depth-4 prefetch slots (static registers via 4-unrolled loop)
    ushort4 gq[4];
#pragma unroll
    for (int d = 0; d < 4; d++) {
        const int t = dir ? (TT - 1 - d) : d;
        gq[d] = *(const ushort4*)(gb + (size_t)t * G4);
    }
    block_sync_lds();

    for (int sb = 0; sb < TT; sb += 4) {
#pragma unroll
        for (int d = 0; d < 4; d++) {
            const int s = sb + d;
            const int t = dir ? (TT - 1 - s) : s;
            const int buf = s & 1;

            // A fragment: same-address broadcast read of h (all rows = h; free in LDS banks)
            bf16x8 afrag[4];
#pragma unroll
            for (int kc = 0; kc < 4; kc++)
                afrag[kc] = __builtin_bit_cast(bf16x8, *(const uint4*)&h_lds[buf][kc * 32 + quad * 8]);

            f32x4 acc[4];
#pragma unroll
            for (int p = 0; p < 4; p++) {
                f32x4 a = {0.f, 0.f, 0.f, 0.f};
#pragma unroll
                for (int kc = 0; kc < 4; kc++)
                    a = __builtin_amdgcn_mfma_f32_16x16x32_bf16(afrag[kc], bfrag[p][kc], a, 0, 0, 0);
                acc[p] = a;
            }

            if (dense) {
                const float gi = acc[0][0] + bf2f(gq[d].x);
                const float gf = acc[1][0] + bf2f(gq[d].y);
                const float gg = acc[2][0] + bf2f(gq[d].z);
                const float go = acc[3][0] + bf2f(gq[d].w);
                const float ig = sigm(gi);
                const float fg = sigm(gf);
                const float gt = tanh_f(gg);
                const float og = sigm(go);
                c = fg * c + ig * gt;
                const float h = og * tanh_f(c);
                const unsigned short hb = f2bf(h);
                h_lds[buf ^ 1][hcol] = hb;
                out[((size_t)b * TT + t) * (2 * HH) + dir * HH + hcol] = hb;
            }

            // refill slot d with step s+4's preacts (consumed 4 steps later; stays in flight)
            {
                int sn = s + 4;
                int tn = dir ? (TT - 1 - sn) : sn;
                tn = tn < 0 ? 0 : (tn > TT - 1 ? TT - 1 : tn);
                gq[d] = *(const ushort4*)(gb + (size_t)tn * G4);
            }
            block_sync_lds();
        }
    }
}

// ---------------- emissions: out1 [65536,256] bf16 @ fc_w^T [3,256] + fc_b ----------------
__global__ __launch_bounds__(256) void emis_kernel(
    const unsigned short* __restrict__ out1,
    const float* __restrict__ fcw, const float* __restrict__ fcb,
    float* __restrict__ dout)
{
    if (blockIdx.x == 0 && threadIdx.x == 0) dout[0] = 0.f; // init for CRF atomics

    __shared__ float wsm[NTAG * 256];
    for (int i = threadIdx.x; i < NTAG * 256; i += 256) wsm[i] = fcw[i];
    __syncthreads();

    const int bt = blockIdx.x * 256 + threadIdx.x;
    float a0 = fcb[0], a1 = fcb[1], a2 = fcb[2];
    const uint4* row = (const uint4*)(out1 + (size_t)bt * 256);
#pragma unroll 4
    for (int k8 = 0; k8 < 32; k8++) {
        uint4 u = row[k8];
        const int kb = k8 * 8;
        uint32_t p[4] = {u.x, u.y, u.z, u.w};
#pragma unroll
        for (int e = 0; e < 4; e++) {
            float flo = __builtin_bit_cast(float, p[e] << 16);
            float fhi = __builtin_bit_cast(float, p[e] & 0xFFFF0000u);
            const int k = kb + 2 * e;
            a0 = fmaf(flo, wsm[0 * 256 + k], a0);
            a1 = fmaf(flo, wsm[1 * 256 + k], a1);
            a2 = fmaf(flo, wsm[2 * 256 + k], a2);
            a0 = fmaf(fhi, wsm[0 * 256 + k + 1], a0);
            a1 = fmaf(fhi, wsm[1 * 256 + k + 1], a1);
            a2 = fmaf(fhi, wsm[2 * 256 + k + 1], a2);
        }
    }
    dout[1 + (size_t)bt * 3 + 0] = a0;
    dout[1 + (size_t)bt * 3 + 1] = a1;
    dout[1 + (size_t)bt * 3 + 2] = a2;
}

// ---------------- CRF NLL: log-semiring parallel scan ----------------
__device__ __forceinline__ float sel3(int i, float a, float b, float c) {
    return i == 0 ? a : (i == 1 ? b : c);
}
__device__ __forceinline__ float lse3(float a, float b, float c) {
    float m = fmaxf(a, fmaxf(b, c));
    float s = exp2f((a - m) * 1.44269504f) + exp2f((b - m) * 1.44269504f) + exp2f((c - m) * 1.44269504f);
    return m + log2f(s) * 0.69314718f;
}

// grid (64): one block (one wave) per batch. Thread th folds transition matrices
// t in [1+16th, 1+16th+16); 6-level shuffle tree combines; numerator by shuffle-add.
__global__ __launch_bounds__(64) void crf_kernel(
    const int* __restrict__ tags,
    const float* __restrict__ start, const float* __restrict__ end,
    const float* __restrict__ trans, float* __restrict__ dout)
{
    const int b = blockIdx.x;
    const int th = threadIdx.x;
    const float* em = dout + 1 + (size_t)b * TT * 3;
    const int* tg = tags + (size_t)b * TT;

    float tr[3][3];
#pragma unroll
    for (int i = 0; i < 3; i++)
#pragma unroll
        for (int j = 0; j < 3; j++) tr[i][j] = trans[i * 3 + j];

    // log-semiring identity
    float P[3][3];
#pragma unroll
    for (int i = 0; i < 3; i++)
#pragma unroll
        for (int j = 0; j < 3; j++) P[i][j] = (i == j) ? 0.f : -1e30f;

    const int t0 = 1 + 16 * th;
    float numpart = 0.f;
    int tprev = tg[t0 - 1];

    for (int d = 0; d < 16; d++) {
        const int t = t0 + d;
        if (t < TT) {
            const float e0 = em[3 * t + 0], e1 = em[3 * t + 1], e2 = em[3 * t + 2];
            // P = P (*) M_t, where M_t[k][j] = tr[k][j] + e_j
            float N[3][3];
#pragma unroll
            for (int i = 0; i < 3; i++) {
                N[i][0] = lse3(P[i][0] + tr[0][0], P[i][1] + tr[1][0], P[i][2] + tr[2][0]) + e0;
                N[i][1] = lse3(P[i][0] + tr[0][1], P[i][1] + tr[1][1], P[i][2] + tr[2][1]) + e1;
                N[i][2] = lse3(P[i][0] + tr[0][2], P[i][1] + tr[1][2], P[i][2] + tr[2][2]) + e2;
            }
#pragma unroll
            for (int i = 0; i < 3; i++)
#pragma unroll
                for (int j = 0; j < 3; j++) P[i][j] = N[i][j];
            const int tc = tg[t];
            numpart += sel3(tc, e0, e1, e2) + sel3(tprev,
                         sel3(tc, tr[0][0], tr[0][1], tr[0][2]),
                         sel3(tc, tr[1][0], tr[1][1], tr[1][2]),
                         sel3(tc, tr[2][0], tr[2][1], tr[2][2]));
            tprev = tc;
        }
    }

    // tree combine: chunk order is by lane index; left = lower lane
#pragma unroll
    for (int off = 1; off < 64; off <<= 1) {
        float Q[3][3];
#pragma unroll
        for (int i = 0; i < 3; i++)
#pragma unroll
            for (int j = 0; j < 3; j++) Q[i][j] = __shfl_xor(P[i][j], off, 64);
        const bool hi = (th & off) != 0;
        float L[3][3], R[3][3];
#pragma unroll
        for (int i = 0; i < 3; i++)
#pragma unroll
            for (int j = 0; j < 3; j++) {
                L[i][j] = hi ? Q[i][j] : P[i][j];
                R[i][j] = hi ? P[i][j] : Q[i][j];
            }
#pragma unroll
        for (int i = 0; i < 3; i++)
#pragma unroll
            for (int j = 0; j < 3; j++)
                P[i][j] = lse3(L[i][0] + R[0][j], L[i][1] + R[1][j], L[i][2] + R[2][j]);
        numpart += __shfl_xor(numpart, off, 64);
    }

    if (th == 0) {
        const int tg0 = tg[0], tgL = tg[TT - 1];
        const float a0 = start[0] + em[0], a1 = start[1] + em[1], a2 = start[2] + em[2];
        const float f0 = lse3(a0 + P[0][0], a1 + P[1][0], a2 + P[2][0]);
        const float f1 = lse3(a0 + P[0][1], a1 + P[1][1], a2 + P[2][1]);
        const float f2 = lse3(a0 + P[0][2], a1 + P[1][2], a2 + P[2][2]);
        const float logZ = lse3(f0 + end[0], f1 + end[1], f2 + end[2]);
        const float num = sel3(tg0, start[0], start[1], start[2]) +
                          sel3(tg0, em[0], em[1], em[2]) + numpart +
                          sel3(tgL, end[0], end[1], end[2]);
        atomicAdd(&dout[0], (logZ - num) * (1.0f / (float)BB));
    }
}

// ---------------- launch ----------------
extern "C" void kernel_launch(void* const* d_in, const int* in_sizes, int n_in,
                              void* d_out, int out_size, void* d_ws, size_t ws_size,
                              hipStream_t stream) {
    const float* x        = (const float*)d_in[0];
    const int*   tags     = (const int*)d_in[1];
    const float* w_ih_l0  = (const float*)d_in[2];
    const float* w_hh_l0  = (const float*)d_in[3];
    const float* b_ih_l0  = (const float*)d_in[4];
    const float* b_hh_l0  = (const float*)d_in[5];
    const float* w_ih_l0r = (const float*)d_in[6];
    const float* w_hh_l0r = (const float*)d_in[7];
    const float* b_ih_l0r = (const float*)d_in[8];
    const float* b_hh_l0r = (const float*)d_in[9];
    const float* w_ih_l1  = (const float*)d_in[10];
    const float* w_hh_l1  = (const float*)d_in[11];
    const float* b_ih_l1  = (const float*)d_in[12];
    const float* b_hh_l1  = (const float*)d_in[13];
    const float* w_ih_l1r = (const float*)d_in[14];
    const float* w_hh_l1r = (const float*)d_in[15];
    const float* b_ih_l1r = (const float*)d_in[16];
    const float* b_hh_l1r = (const float*)d_in[17];
    const float* fc_w     = (const float*)d_in[18];
    const float* fc_b     = (const float*)d_in[19];
    const float* crf_start= (const float*)d_in[20];
    const float* crf_end  = (const float*)d_in[21];
    const float* crf_trans= (const float*)d_in[22];
    float* dout = (float*)d_out;

    uint8_t* ws = (uint8_t*)d_ws;
    // workspace layout (bytes)
    unsigned short* xb   = (unsigned short*)(ws + 0);          // 33.5 MB, reused as out1 later
    unsigned short* out1 = xb;
    unsigned short* out0 = (unsigned short*)(ws + 33554432);   // 33.5 MB
    unsigned short* Gf   = (unsigned short*)(ws + 67108864);   // 67 MB
    unsigned short* Gr   = (unsigned short*)(ws + 134217728);  // 67 MB
    unsigned short* wb0  = (unsigned short*)(ws + 201326592);  // 4 x 256 KB
    unsigned short* wb0r = wb0 + 131072;
    unsigned short* wb1  = wb0 + 262144;
    unsigned short* wb1r = wb0 + 393216;

    // 1. convert x and the 4 w_ih matrices to bf16
    cvt4_kernel<<<dim3((16777216 / 4 + 255) / 256), dim3(256), 0, stream>>>(x, xb, 16777216 / 4);
    cvt4_kernel<<<dim3(128), dim3(256), 0, stream>>>(w_ih_l0,  wb0,  131072 / 4);
    cvt4_kernel<<<dim3(128), dim3(256), 0, stream>>>(w_ih_l0r, wb0r, 131072 / 4);
    cvt4_kernel<<<dim3(128), dim3(256), 0, stream>>>(w_ih_l1,  wb1,  131072 / 4);
    cvt4_kernel<<<dim3(128), dim3(256), 0, stream>>>(w_ih_l1r, wb1r, 131072 / 4);

    // 2. layer 0: input projection + MFMA scan
    gemm_ih<<<dim3(1024, 4, 2), dim3(256), 0, stream>>>(
        xb, wb0, wb0r, b_ih_l0, b_hh_l0, b_ih_l0r, b_hh_l0r, Gf, Gr);
    lstm_scan_mfma<<<dim3(64, 2), dim3(512), 0, stream>>>(Gf, Gr, w_hh_l0, w_hh_l0r, out0);

    // 3. layer 1: input projection (reusing G buffers) + MFMA scan
    gemm_ih<<<dim3(1024, 4, 2), dim3(256), 0, stream>>>(
        out0, wb1, wb1r, b_ih_l1, b_hh_l1, b_ih_l1r, b_hh_l1r, Gf, Gr);
    lstm_scan_mfma<<<dim3(64, 2), dim3(512), 0, stream>>>(Gf, Gr, w_hh_l1, w_hh_l1r, out1);

    // 4. emissions (also zeroes dout[0] for the CRF atomics)
    emis_kernel<<<dim3(256), dim3(256), 0, stream>>>(out1, fc_w, fc_b, dout);

    // 5. CRF NLL -> dout[0] (parallel scan, one block per batch)
    crf_kernel<<<dim3(64), dim3(64), 0, stream>>>(tags, crf_start, crf_end, crf_trans, dout);
}

// Round 6
// 1472.304 us; speedup vs baseline: 1.8222x; 1.1019x over previous
//
#include <hip/hip_runtime.h>
#include <cstdint>

// Problem constants
#define BB 64
#define TT 1024
#define DD 256
#define HH 128
#define G4 512   // 4*H
#define NTAG 3

typedef __attribute__((ext_vector_type(8))) short bf16x8;
typedef __attribute__((ext_vector_type(4))) float f32x4;
typedef __attribute__((ext_vector_type(4))) int i32x4;

__device__ __forceinline__ unsigned short f2bf(float f) {
    uint32_t u = __builtin_bit_cast(uint32_t, f);
    uint32_t r = (u + 0x7FFFu + ((u >> 16) & 1u)) >> 16;
    return (unsigned short)r;
}
__device__ __forceinline__ float bf2f(unsigned short s) {
    uint32_t u = ((uint32_t)s) << 16;
    return __builtin_bit_cast(float, u);
}
// raw HW transcendentals: v_exp_f32 / v_rcp_f32
__device__ __forceinline__ float sigm(float x) {
    return __builtin_amdgcn_rcpf(1.f + __builtin_amdgcn_exp2f(x * -1.44269504f));
}
__device__ __forceinline__ float tanh_f(float x) {
    // tanh(x) = 1 - 2/(1+e^{2x})
    return 1.f - 2.f * __builtin_amdgcn_rcpf(1.f + __builtin_amdgcn_exp2f(x * 2.88539008f));
}

// LDS-only barrier: s_waitcnt vmcnt(63) expcnt(7) lgkmcnt(0) + s_barrier.
// Does NOT drain the vmem FIFO (global loads/stores stay in flight), unlike
// __syncthreads() which emits vmcnt(0) before s_barrier.
__device__ __forceinline__ void block_sync_lds() {
    __builtin_amdgcn_s_waitcnt(0xC07F);
    __builtin_amdgcn_s_barrier();
}

// ---------------- fp32 -> bf16 conversion (vectorized x4) ----------------
__global__ void cvt4_kernel(const float* __restrict__ in, unsigned short* __restrict__ out, int n4) {
    int idx = blockIdx.x * blockDim.x + threadIdx.x;
    if (idx < n4) {
        float4 v = ((const float4*)in)[idx];
        ushort4 o;
        o.x = f2bf(v.x); o.y = f2bf(v.y); o.z = f2bf(v.z); o.w = f2bf(v.w);
        ((ushort4*)out)[idx] = o;
    }
}

// ---------------- input-projection GEMM: G = A @ W^T + b_ih + b_hh ----------------
// A: [65536, 256] bf16 row-major. W: [512, 256] bf16 row-major (N,K).
// G layout: [row][hcol*4 + gate]  (gate-interleaved: scan loads 4 gates as one 8B read).
// grid (1024, 4, 2): x = 64-row M block, y = 32-hcol strip (all 4 gates), z = direction.
__global__ __launch_bounds__(256) void gemm_ih(
    const unsigned short* __restrict__ A,
    const unsigned short* __restrict__ W0, const unsigned short* __restrict__ W1,
    const float* __restrict__ bih0, const float* __restrict__ bhh0,
    const float* __restrict__ bih1, const float* __restrict__ bhh1,
    unsigned short* __restrict__ G0, unsigned short* __restrict__ G1)
{
    const int dir = blockIdx.z;
    const unsigned short* W = dir ? W1 : W0;
    const float* bih = dir ? bih1 : bih0;
    const float* bhh = dir ? bhh1 : bhh0;
    unsigned short* G = dir ? G1 : G0;

    const int wave = threadIdx.x >> 6;
    const int lane = threadIdx.x & 63;
    const int m16 = lane & 15;
    const int quad = lane >> 4;

    const int rowA = blockIdx.x * 64 + wave * 16 + m16;
    const int hcol0 = blockIdx.y * 32;

    // preload 8 A fragments (K = 8 x 32)
    bf16x8 afrag[8];
    const uint4* Abase = (const uint4*)(A + (size_t)rowA * DD + quad * 8);
#pragma unroll
    for (int kk = 0; kk < 8; kk++) {
        uint4 u = Abase[kk * 2];
        afrag[kk] = __builtin_bit_cast(bf16x8, u);
    }

#pragma unroll
    for (int p = 0; p < 8; p++) {
        const int g = p & 3;       // gate
        const int j = p >> 2;      // 16-col half of the 32-hcol strip
        const int n = g * 128 + hcol0 + j * 16 + m16;
        f32x4 acc = {0.f, 0.f, 0.f, 0.f};
        const uint4* Wbase = (const uint4*)(W + (size_t)n * DD + quad * 8);
#pragma unroll
        for (int kk = 0; kk < 8; kk++) {
            uint4 u = Wbase[kk * 2];
            bf16x8 bfrag = __builtin_bit_cast(bf16x8, u);
            acc = __builtin_amdgcn_mfma_f32_16x16x32_bf16(afrag[kk], bfrag, acc, 0, 0, 0);
        }
        const float bias = bih[n] + bhh[n];
        const int outRowBase = blockIdx.x * 64 + wave * 16 + quad * 4;
        const int col = ((n & 127) << 2) + g;   // hcol*4 + gate
#pragma unroll
        for (int r = 0; r < 4; r++) {
            G[(size_t)(outRowBase + r) * G4 + col] = f2bf(acc[r] + bias);
        }
    }
}

// ---------------- MFMA LSTM recurrent scan (i8 recurrence) ----------------
// grid (64, 2): x = batch, y = direction. 512 threads = 8 waves.
// Wave wv owns hcols [16wv,16wv+16) for ALL 4 gates (N-tiles at n = 128p + 16wv).
// Recurrent matmul in int8: w_hh quantized at scale 1024 (max|w|*1024 = 90.5 < 127),
// h quantized at scale 127; v_mfma_i32_16x16x64_i8 does K=128 in 2 instructions at
// ~2x the bf16 FLOP rate -> per-SIMD MFMA exec ~326 cyc/step vs ~512 for bf16.
// Gates stay in acc registers; lane (n16, quad==0) holds i,f,g,o for its hcol.
// h (i8) double-buffered in LDS, read via same-address broadcast (A rows all = h).
// G preacts (gate-interleaved) prefetched 4 steps ahead, one 8B load/lane/step.
__global__ __launch_bounds__(512, 2) void lstm_scan_mfma(
    const unsigned short* __restrict__ Gf, const unsigned short* __restrict__ Gr,
    const float* __restrict__ whh_f, const float* __restrict__ whh_r,
    unsigned short* __restrict__ out)
{
    const int b = blockIdx.x;
    const int dir = blockIdx.y;
    const unsigned short* G = dir ? Gr : Gf;
    const float* W = dir ? whh_r : whh_f;

    const int tid = threadIdx.x;
    const int wv = tid >> 6;
    const int lane = tid & 63;
    const int n16 = lane & 15;
    const int quad = lane >> 4;

    __shared__ __align__(16) signed char h8[2][HH];

    // preload i8 b-fragments: tile p covers n = 128*p + wv*16 + n16; B[k][n] = w_hh[n][k]
    // k-mapping per lane: k = kc*64 + quad*16 + j (byte j of the 16B fragment)
    i32x4 bfrag[4][2];
#pragma unroll
    for (int p = 0; p < 4; p++) {
        const int n = 128 * p + wv * 16 + n16;
        const float* Wr = W + (size_t)n * HH;
#pragma unroll
        for (int kc = 0; kc < 2; kc++) {
            union { signed char c[16]; i32x4 v; } u;
#pragma unroll
            for (int j = 0; j < 16; j++) {
                float w = Wr[kc * 64 + quad * 16 + j] * 1024.f;
                int q = (int)rintf(w);
                q = q > 127 ? 127 : (q < -127 ? -127 : q);
                u.c[j] = (signed char)q;
            }
            bfrag[p][kc] = u.v;
        }
    }

    if (tid < HH) h8[0][tid] = 0;

    const bool dense = (quad == 0);
    const int hcol = wv * 16 + n16;
    float c = 0.f;
    const float INV = 1.f / 130048.f;   // 1/(1024*127)

    // per-lane G base: 4 contiguous gate preacts for this hcol (quads duplicate -> same lines)
    const unsigned short* gb = G + (size_t)b * TT * G4 + hcol * 4;

    // depth-4 prefetch slots (static registers via 4-unrolled loop)
    ushort4 gq[4];
#pragma unroll
    for (int d = 0; d < 4; d++) {
        const int t = dir ? (TT - 1 - d) : d;
        gq[d] = *(const ushort4*)(gb + (size_t)t * G4);
    }
    block_sync_lds();

    for (int sb = 0; sb < TT; sb += 4) {
#pragma unroll
        for (int d = 0; d < 4; d++) {
            const int s = sb + d;
            const int t = dir ? (TT - 1 - s) : s;
            const int buf = s & 1;

            // A fragments: same-address broadcast read of i8 h (all rows = h)
            i32x4 af[2];
#pragma unroll
            for (int kc = 0; kc < 2; kc++)
                af[kc] = __builtin_bit_cast(i32x4, *(const uint4*)&h8[buf][kc * 64 + quad * 16]);

            i32x4 acc[4];
#pragma unroll
            for (int p = 0; p < 4; p++) {
                i32x4 a = {0, 0, 0, 0};
                a = __builtin_amdgcn_mfma_i32_16x16x64_i8(af[0], bfrag[p][0], a, 0, 0, 0);
                a = __builtin_amdgcn_mfma_i32_16x16x64_i8(af[1], bfrag[p][1], a, 0, 0, 0);
                acc[p] = a;
            }

            if (dense) {
                const float gi = (float)acc[0][0] * INV + bf2f(gq[d].x);
                const float gf = (float)acc[1][0] * INV + bf2f(gq[d].y);
                const float gg = (float)acc[2][0] * INV + bf2f(gq[d].z);
                const float go = (float)acc[3][0] * INV + bf2f(gq[d].w);
                const float ig = sigm(gi);
                const float fg = sigm(gf);
                const float gt = tanh_f(gg);
                const float og = sigm(go);
                c = fg * c + ig * gt;
                const float h = og * tanh_f(c);
                h8[buf ^ 1][hcol] = (signed char)(int)rintf(h * 127.f);
                out[((size_t)b * TT + t) * (2 * HH) + dir * HH + hcol] = f2bf(h);
            }

            // refill slot d with step s+4's preacts (consumed 4 steps later; stays in flight)
            {
                int sn = s + 4;
                int tn = dir ? (TT - 1 - sn) : sn;
                tn = tn < 0 ? 0 : (tn > TT - 1 ? TT - 1 : tn);
                gq[d] = *(const ushort4*)(gb + (size_t)tn * G4);
            }
            block_sync_lds();
        }
    }
}

// ---------------- emissions: out1 [65536,256] bf16 @ fc_w^T [3,256] + fc_b ----------------
__global__ __launch_bounds__(256) void emis_kernel(
    const unsigned short* __restrict__ out1,
    const float* __restrict__ fcw, const float* __restrict__ fcb,
    float* __restrict__ dout)
{
    if (blockIdx.x == 0 && threadIdx.x == 0) dout[0] = 0.f; // init for CRF atomics

    __shared__ float wsm[NTAG * 256];
    for (int i = threadIdx.x; i < NTAG * 256; i += 256) wsm[i] = fcw[i];
    __syncthreads();

    const int bt = blockIdx.x * 256 + threadIdx.x;
    float a0 = fcb[0], a1 = fcb[1], a2 = fcb[2];
    const uint4* row = (const uint4*)(out1 + (size_t)bt * 256);
#pragma unroll 4
    for (int k8 = 0; k8 < 32; k8++) {
        uint4 u = row[k8];
        const int kb = k8 * 8;
        uint32_t p[4] = {u.x, u.y, u.z, u.w};
#pragma unroll
        for (int e = 0; e < 4; e++) {
            float flo = __builtin_bit_cast(float, p[e] << 16);
            float fhi = __builtin_bit_cast(float, p[e] & 0xFFFF0000u);
            const int k = kb + 2 * e;
            a0 = fmaf(flo, wsm[0 * 256 + k], a0);
            a1 = fmaf(flo, wsm[1 * 256 + k], a1);
            a2 = fmaf(flo, wsm[2 * 256 + k], a2);
            a0 = fmaf(fhi, wsm[0 * 256 + k + 1], a0);
            a1 = fmaf(fhi, wsm[1 * 256 + k + 1], a1);
            a2 = fmaf(fhi, wsm[2 * 256 + k + 1], a2);
        }
    }
    dout[1 + (size_t)bt * 3 + 0] = a0;
    dout[1 + (size_t)bt * 3 + 1] = a1;
    dout[1 + (size_t)bt * 3 + 2] = a2;
}

// ---------------- CRF NLL: log-semiring parallel scan ----------------
__device__ __forceinline__ float sel3(int i, float a, float b, float c) {
    return i == 0 ? a : (i == 1 ? b : c);
}
__device__ __forceinline__ float lse3(float a, float b, float c) {
    float m = fmaxf(a, fmaxf(b, c));
    float s = exp2f((a - m) * 1.44269504f) + exp2f((b - m) * 1.44269504f) + exp2f((c - m) * 1.44269504f);
    return m + log2f(s) * 0.69314718f;
}

// grid (64): one block (one wave) per batch. Thread th folds transition matrices
// t in [1+16th, 1+16th+16); 6-level shuffle tree combines; numerator by shuffle-add.
__global__ __launch_bounds__(64) void crf_kernel(
    const int* __restrict__ tags,
    const float* __restrict__ start, const float* __restrict__ end,
    const float* __restrict__ trans, float* __restrict__ dout)
{
    const int b = blockIdx.x;
    const int th = threadIdx.x;
    const float* em = dout + 1 + (size_t)b * TT * 3;
    const int* tg = tags + (size_t)b * TT;

    float tr[3][3];
#pragma unroll
    for (int i = 0; i < 3; i++)
#pragma unroll
        for (int j = 0; j < 3; j++) tr[i][j] = trans[i * 3 + j];

    // log-semiring identity
    float P[3][3];
#pragma unroll
    for (int i = 0; i < 3; i++)
#pragma unroll
        for (int j = 0; j < 3; j++) P[i][j] = (i == j) ? 0.f : -1e30f;

    const int t0 = 1 + 16 * th;
    float numpart = 0.f;
    int tprev = tg[t0 - 1];

    for (int d = 0; d < 16; d++) {
        const int t = t0 + d;
        if (t < TT) {
            const float e0 = em[3 * t + 0], e1 = em[3 * t + 1], e2 = em[3 * t + 2];
            float N[3][3];
#pragma unroll
            for (int i = 0; i < 3; i++) {
                N[i][0] = lse3(P[i][0] + tr[0][0], P[i][1] + tr[1][0], P[i][2] + tr[2][0]) + e0;
                N[i][1] = lse3(P[i][0] + tr[0][1], P[i][1] + tr[1][1], P[i][2] + tr[2][1]) + e1;
                N[i][2] = lse3(P[i][0] + tr[0][2], P[i][1] + tr[1][2], P[i][2] + tr[2][2]) + e2;
            }
#pragma unroll
            for (int i = 0; i < 3; i++)
#pragma unroll
                for (int j = 0; j < 3; j++) P[i][j] = N[i][j];
            const int tc = tg[t];
            numpart += sel3(tc, e0, e1, e2) + sel3(tprev,
                         sel3(tc, tr[0][0], tr[0][1], tr[0][2]),
                         sel3(tc, tr[1][0], tr[1][1], tr[1][2]),
                         sel3(tc, tr[2][0], tr[2][1], tr[2][2]));
            tprev = tc;
        }
    }

#pragma unroll
    for (int off = 1; off < 64; off <<= 1) {
        float Q[3][3];
#pragma unroll
        for (int i = 0; i < 3; i++)
#pragma unroll
            for (int j = 0; j < 3; j++) Q[i][j] = __shfl_xor(P[i][j], off, 64);
        const bool hi = (th & off) != 0;
        float L[3][3], R[3][3];
#pragma unroll
        for (int i = 0; i < 3; i++)
#pragma unroll
            for (int j = 0; j < 3; j++) {
                L[i][j] = hi ? Q[i][j] : P[i][j];
                R[i][j] = hi ? P[i][j] : Q[i][j];
            }
#pragma unroll
        for (int i = 0; i < 3; i++)
#pragma unroll
            for (int j = 0; j < 3; j++)
                P[i][j] = lse3(L[i][0] + R[0][j], L[i][1] + R[1][j], L[i][2] + R[2][j]);
        numpart += __shfl_xor(numpart, off, 64);
    }

    if (th == 0) {
        const int tg0 = tg[0], tgL = tg[TT - 1];
        const float a0 = start[0] + em[0], a1 = start[1] + em[1], a2 = start[2] + em[2];
        const float f0 = lse3(a0 + P[0][0], a1 + P[1][0], a2 + P[2][0]);
        const float f1 = lse3(a0 + P[0][1], a1 + P[1][1], a2 + P[2][1]);
        const float f2 = lse3(a0 + P[0][2], a1 + P[1][2], a2 + P[2][2]);
        const float logZ = lse3(f0 + end[0], f1 + end[1], f2 + end[2]);
        const float num = sel3(tg0, start[0], start[1], start[2]) +
                          sel3(tg0, em[0], em[1], em[2]) + numpart +
                          sel3(tgL, end[0], end[1], end[2]);
        atomicAdd(&dout[0], (logZ - num) * (1.0f / (float)BB));
    }
}

// ---------------- launch ----------------
extern "C" void kernel_launch(void* const* d_in, const int* in_sizes, int n_in,
                              void* d_out, int out_size, void* d_ws, size_t ws_size,
                              hipStream_t stream) {
    const float* x        = (const float*)d_in[0];
    const int*   tags     = (const int*)d_in[1];
    const float* w_ih_l0  = (const float*)d_in[2];
    const float* w_hh_l0  = (const float*)d_in[3];
    const float* b_ih_l0  = (const float*)d_in[4];
    const float* b_hh_l0  = (const float*)d_in[5];
    const float* w_ih_l0r = (const float*)d_in[6];
    const float* w_hh_l0r = (const float*)d_in[7];
    const float* b_ih_l0r = (const float*)d_in[8];
    const float* b_hh_l0r = (const float*)d_in[9];
    const float* w_ih_l1  = (const float*)d_in[10];
    const float* w_hh_l1  = (const float*)d_in[11];
    const float* b_ih_l1  = (const float*)d_in[12];
    const float* b_hh_l1  = (const float*)d_in[13];
    const float* w_ih_l1r = (const float*)d_in[14];
    const float* w_hh_l1r = (const float*)d_in[15];
    const float* b_ih_l1r = (const float*)d_in[16];
    const float* b_hh_l1r = (const float*)d_in[17];
    const float* fc_w     = (const float*)d_in[18];
    const float* fc_b     = (const float*)d_in[19];
    const float* crf_start= (const float*)d_in[20];
    const float* crf_end  = (const float*)d_in[21];
    const float* crf_trans= (const float*)d_in[22];
    float* dout = (float*)d_out;

    uint8_t* ws = (uint8_t*)d_ws;
    // workspace layout (bytes)
    unsigned short* xb   = (unsigned short*)(ws + 0);          // 33.5 MB, reused as out1 later
    unsigned short* out1 = xb;
    unsigned short* out0 = (unsigned short*)(ws + 33554432);   // 33.5 MB
    unsigned short* Gf   = (unsigned short*)(ws + 67108864);   // 67 MB
    unsigned short* Gr   = (unsigned short*)(ws + 134217728);  // 67 MB
    unsigned short* wb0  = (unsigned short*)(ws + 201326592);  // 4 x 256 KB
    unsigned short* wb0r = wb0 + 131072;
    unsigned short* wb1  = wb0 + 262144;
    unsigned short* wb1r = wb0 + 393216;

    // 1. convert x and the 4 w_ih matrices to bf16
    cvt4_kernel<<<dim3((16777216 / 4 + 255) / 256), dim3(256), 0, stream>>>(x, xb, 16777216 / 4);
    cvt4_kernel<<<dim3(128), dim3(256), 0, stream>>>(w_ih_l0,  wb0,  131072 / 4);
    cvt4_kernel<<<dim3(128), dim3(256), 0, stream>>>(w_ih_l0r, wb0r, 131072 / 4);
    cvt4_kernel<<<dim3(128), dim3(256), 0, stream>>>(w_ih_l1,  wb1,  131072 / 4);
    cvt4_kernel<<<dim3(128), dim3(256), 0, stream>>>(w_ih_l1r, wb1r, 131072 / 4);

    // 2. layer 0: input projection + MFMA scan
    gemm_ih<<<dim3(1024, 4, 2), dim3(256), 0, stream>>>(
        xb, wb0, wb0r, b_ih_l0, b_hh_l0, b_ih_l0r, b_hh_l0r, Gf, Gr);
    lstm_scan_mfma<<<dim3(64, 2), dim3(512), 0, stream>>>(Gf, Gr, w_hh_l0, w_hh_l0r, out0);

    // 3. layer 1: input projection (reusing G buffers) + MFMA scan
    gemm_ih<<<dim3(1024, 4, 2), dim3(256), 0, stream>>>(
        out0, wb1, wb1r, b_ih_l1, b_hh_l1, b_ih_l1r, b_hh_l1r, Gf, Gr);
    lstm_scan_mfma<<<dim3(64, 2), dim3(512), 0, stream>>>(Gf, Gr, w_hh_l1, w_hh_l1r, out1);

    // 4. emissions (also zeroes dout[0] for the CRF atomics)
    emis_kernel<<<dim3(256), dim3(256), 0, stream>>>(out1, fc_w, fc_b, dout);

    // 5. CRF NLL -> dout[0] (parallel scan, one block per batch)
    crf_kernel<<<dim3(64), dim3(64), 0, stream>>>(tags, crf_start, crf_end, crf_trans, dout);
}

// Round 7
// 1168.377 us; speedup vs baseline: 2.2961x; 1.2601x over previous
//
#include <hip/hip_runtime.h>
#include <cstdint>

// Problem constants
#define BB 64
#define TT 1024
#define DD 256
#define HH 128
#define G4 512   // 4*H
#define NTAG 3

typedef __attribute__((ext_vector_type(8))) short bf16x8;
typedef __attribute__((ext_vector_type(4))) float f32x4;
typedef __attribute__((ext_vector_type(4))) int i32x4;

__device__ __forceinline__ unsigned short f2bf(float f) {
    uint32_t u = __builtin_bit_cast(uint32_t, f);
    uint32_t r = (u + 0x7FFFu + ((u >> 16) & 1u)) >> 16;
    return (unsigned short)r;
}
__device__ __forceinline__ float bf2f(unsigned short s) {
    uint32_t u = ((uint32_t)s) << 16;
    return __builtin_bit_cast(float, u);
}
// raw HW transcendentals: v_exp_f32 / v_rcp_f32
__device__ __forceinline__ float sigm(float x) {
    return __builtin_amdgcn_rcpf(1.f + __builtin_amdgcn_exp2f(x * -1.44269504f));
}
__device__ __forceinline__ float tanh_f(float x) {
    return 1.f - 2.f * __builtin_amdgcn_rcpf(1.f + __builtin_amdgcn_exp2f(x * 2.88539008f));
}

// LDS-only barrier (no vmem drain) — scan kernel only.
__device__ __forceinline__ void block_sync_lds() {
    __builtin_amdgcn_s_waitcnt(0xC07F);
    __builtin_amdgcn_s_barrier();
}

// async global->LDS, 16B per lane; lds base must be wave-uniform (dest = base + lane*16)
#define ASYNC16(gp, lp) \
    __builtin_amdgcn_global_load_lds((const __attribute__((address_space(1))) unsigned int*)(gp), \
                                     (__attribute__((address_space(3))) unsigned int*)(lp), 16, 0, 0)

// ---------------- fp32 -> bf16 conversion (vectorized x4) ----------------
__global__ void cvt4_kernel(const float* __restrict__ in, unsigned short* __restrict__ out, int n4) {
    int idx = blockIdx.x * blockDim.x + threadIdx.x;
    if (idx < n4) {
        float4 v = ((const float4*)in)[idx];
        ushort4 o;
        o.x = f2bf(v.x); o.y = f2bf(v.y); o.z = f2bf(v.z); o.w = f2bf(v.w);
        ((ushort4*)out)[idx] = o;
    }
}

// ---------------- input-projection GEMM (m97-style LDS-staged) ----------------
// G = A @ W^T + b_ih + b_hh.  A: [65536,256] bf16. W: [512,256] bf16 (N,K).
// G layout: [row][hcol*4 + gate] (gate-interleaved for the scan's single 8B load).
// grid (512, 4, 2): x = 128-row M tile, y = gate (= N tile of 128 cols), z = dir.
// Block 256 thr = 4 waves as 2x2; wave tile 64x64; BK=64, K=256 -> 4 staged iters;
// A/B tiles staged via global_load_lds width 16 (8 insts/wave/iter).
__global__ __launch_bounds__(256) void gemm_ih(
    const unsigned short* __restrict__ A,
    const unsigned short* __restrict__ W0, const unsigned short* __restrict__ W1,
    const float* __restrict__ bih0, const float* __restrict__ bhh0,
    const float* __restrict__ bih1, const float* __restrict__ bhh1,
    unsigned short* __restrict__ G0, unsigned short* __restrict__ G1)
{
    const int dir = blockIdx.z;
    const unsigned short* W = dir ? W1 : W0;
    const float* bih = dir ? bih1 : bih0;
    const float* bhh = dir ? bhh1 : bhh0;
    unsigned short* G = dir ? G1 : G0;

    const int gate = blockIdx.y;
    const int m0 = blockIdx.x * 128;

    const int tid = threadIdx.x;
    const int wv = tid >> 6;
    const int lane = tid & 63;
    const int m16 = lane & 15;
    const int quad = lane >> 4;
    const int wave_m = wv & 1;
    const int wave_n = wv >> 1;

    __shared__ __align__(16) unsigned short As[128 * 64];
    __shared__ __align__(16) unsigned short Bs[128 * 64];

    f32x4 acc[4][4];
#pragma unroll
    for (int i = 0; i < 4; i++)
#pragma unroll
        for (int j = 0; j < 4; j++) acc[i][j] = (f32x4){0.f, 0.f, 0.f, 0.f};

    const int lrow = lane >> 3;          // 0..7: row within 8-row segment
    const int lcol = (lane & 7) * 8;     // k element offset (8 bf16 = 16B)

    for (int kt = 0; kt < 4; kt++) {
        // stage A[128][64] and B(=W)[128][64] tiles; wave wv owns segments wv*4..+4
#pragma unroll
        for (int it = 0; it < 4; it++) {
            const int seg = wv * 4 + it;
            const int row = seg * 8 + lrow;
            ASYNC16(A + (size_t)(m0 + row) * DD + kt * 64 + lcol, As + seg * 512);
            ASYNC16(W + (size_t)(gate * 128 + row) * DD + kt * 64 + lcol, Bs + seg * 512);
        }
        __syncthreads();   // drains vmcnt -> staged data visible

#pragma unroll
        for (int kk = 0; kk < 2; kk++) {
            bf16x8 a[4], b[4];
#pragma unroll
            for (int i = 0; i < 4; i++) {
                const int row = wave_m * 64 + i * 16 + m16;
                a[i] = __builtin_bit_cast(bf16x8, *(const uint4*)&As[row * 64 + kk * 32 + quad * 8]);
            }
#pragma unroll
            for (int j = 0; j < 4; j++) {
                const int row = wave_n * 64 + j * 16 + m16;
                b[j] = __builtin_bit_cast(bf16x8, *(const uint4*)&Bs[row * 64 + kk * 32 + quad * 8]);
            }
#pragma unroll
            for (int i = 0; i < 4; i++)
#pragma unroll
                for (int j = 0; j < 4; j++)
                    acc[i][j] = __builtin_amdgcn_mfma_f32_16x16x32_bf16(a[i], b[j], acc[i][j], 0, 0, 0);
        }
        __syncthreads();   // tile consumed; safe to restage
    }

    // epilogue: bias + gate-interleaved store
#pragma unroll
    for (int j = 0; j < 4; j++) {
        const int hcol = wave_n * 64 + j * 16 + m16;
        const int n = gate * 128 + hcol;
        const float bias = bih[n] + bhh[n];
        const int col = hcol * 4 + gate;
#pragma unroll
        for (int i = 0; i < 4; i++) {
            const int rowg = m0 + wave_m * 64 + i * 16 + quad * 4;
#pragma unroll
            for (int r = 0; r < 4; r++) {
                G[(size_t)(rowg + r) * G4 + col] = f2bf(acc[i][j][r] + bias);
            }
        }
    }
}

// ---------------- MFMA LSTM recurrent scan (i8 recurrence) ----------------
// grid (64, 2). 512 threads = 8 waves; wave wv owns hcols [16wv,16wv+16) for all 4 gates.
// w_hh quantized i8 scale 1024; h i8 scale 127; v_mfma_i32_16x16x64_i8, K=128 in 2 inst.
// Gates stay in acc regs; h (i8) double-buffered in LDS (broadcast reads);
// G preacts (gate-interleaved) prefetched 4 steps ahead; LDS-only barrier.
__global__ __launch_bounds__(512, 2) void lstm_scan_mfma(
    const unsigned short* __restrict__ Gf, const unsigned short* __restrict__ Gr,
    const float* __restrict__ whh_f, const float* __restrict__ whh_r,
    unsigned short* __restrict__ out)
{
    const int b = blockIdx.x;
    const int dir = blockIdx.y;
    const unsigned short* G = dir ? Gr : Gf;
    const float* W = dir ? whh_r : whh_f;

    const int tid = threadIdx.x;
    const int wv = tid >> 6;
    const int lane = tid & 63;
    const int n16 = lane & 15;
    const int quad = lane >> 4;

    __shared__ __align__(16) signed char h8[2][HH];

    i32x4 bfrag[4][2];
#pragma unroll
    for (int p = 0; p < 4; p++) {
        const int n = 128 * p + wv * 16 + n16;
        const float* Wr = W + (size_t)n * HH;
#pragma unroll
        for (int kc = 0; kc < 2; kc++) {
            union { signed char c[16]; i32x4 v; } u;
#pragma unroll
            for (int j = 0; j < 16; j++) {
                float w = Wr[kc * 64 + quad * 16 + j] * 1024.f;
                int q = (int)rintf(w);
                q = q > 127 ? 127 : (q < -127 ? -127 : q);
                u.c[j] = (signed char)q;
            }
            bfrag[p][kc] = u.v;
        }
    }

    if (tid < HH) h8[0][tid] = 0;

    const bool dense = (quad == 0);
    const int hcol = wv * 16 + n16;
    float c = 0.f;
    const float INV = 1.f / 130048.f;   // 1/(1024*127)

    const unsigned short* gb = G + (size_t)b * TT * G4 + hcol * 4;

    ushort4 gq[4];
#pragma unroll
    for (int d = 0; d < 4; d++) {
        const int t = dir ? (TT - 1 - d) : d;
        gq[d] = *(const ushort4*)(gb + (size_t)t * G4);
    }
    block_sync_lds();

    for (int sb = 0; sb < TT; sb += 4) {
#pragma unroll
        for (int d = 0; d < 4; d++) {
            const int s = sb + d;
            const int t = dir ? (TT - 1 - s) : s;
            const int buf = s & 1;

            i32x4 af[2];
#pragma unroll
            for (int kc = 0; kc < 2; kc++)
                af[kc] = __builtin_bit_cast(i32x4, *(const uint4*)&h8[buf][kc * 64 + quad * 16]);

            i32x4 acc[4];
#pragma unroll
            for (int p = 0; p < 4; p++) {
                i32x4 a = {0, 0, 0, 0};
                a = __builtin_amdgcn_mfma_i32_16x16x64_i8(af[0], bfrag[p][0], a, 0, 0, 0);
                a = __builtin_amdgcn_mfma_i32_16x16x64_i8(af[1], bfrag[p][1], a, 0, 0, 0);
                acc[p] = a;
            }

            if (dense) {
                const float gi = (float)acc[0][0] * INV + bf2f(gq[d].x);
                const float gf = (float)acc[1][0] * INV + bf2f(gq[d].y);
                const float gg = (float)acc[2][0] * INV + bf2f(gq[d].z);
                const float go = (float)acc[3][0] * INV + bf2f(gq[d].w);
                const float ig = sigm(gi);
                const float fg = sigm(gf);
                const float gt = tanh_f(gg);
                const float og = sigm(go);
                c = fg * c + ig * gt;
                const float h = og * tanh_f(c);
                h8[buf ^ 1][hcol] = (signed char)(int)rintf(h * 127.f);
                out[((size_t)b * TT + t) * (2 * HH) + dir * HH + hcol] = f2bf(h);
            }

            {
                int sn = s + 4;
                int tn = dir ? (TT - 1 - sn) : sn;
                tn = tn < 0 ? 0 : (tn > TT - 1 ? TT - 1 : tn);
                gq[d] = *(const ushort4*)(gb + (size_t)tn * G4);
            }
            block_sync_lds();
        }
    }
}

// ---------------- emissions: out1 [65536,256] bf16 @ fc_w^T [3,256] + fc_b ----------------
__global__ __launch_bounds__(256) void emis_kernel(
    const unsigned short* __restrict__ out1,
    const float* __restrict__ fcw, const float* __restrict__ fcb,
    float* __restrict__ dout)
{
    if (blockIdx.x == 0 && threadIdx.x == 0) dout[0] = 0.f; // init for CRF atomics

    __shared__ float wsm[NTAG * 256];
    for (int i = threadIdx.x; i < NTAG * 256; i += 256) wsm[i] = fcw[i];
    __syncthreads();

    const int bt = blockIdx.x * 256 + threadIdx.x;
    float a0 = fcb[0], a1 = fcb[1], a2 = fcb[2];
    const uint4* row = (const uint4*)(out1 + (size_t)bt * 256);
#pragma unroll 4
    for (int k8 = 0; k8 < 32; k8++) {
        uint4 u = row[k8];
        const int kb = k8 * 8;
        uint32_t p[4] = {u.x, u.y, u.z, u.w};
#pragma unroll
        for (int e = 0; e < 4; e++) {
            float flo = __builtin_bit_cast(float, p[e] << 16);
            float fhi = __builtin_bit_cast(float, p[e] & 0xFFFF0000u);
            const int k = kb + 2 * e;
            a0 = fmaf(flo, wsm[0 * 256 + k], a0);
            a1 = fmaf(flo, wsm[1 * 256 + k], a1);
            a2 = fmaf(flo, wsm[2 * 256 + k], a2);
            a0 = fmaf(fhi, wsm[0 * 256 + k + 1], a0);
            a1 = fmaf(fhi, wsm[1 * 256 + k + 1], a1);
            a2 = fmaf(fhi, wsm[2 * 256 + k + 1], a2);
        }
    }
    dout[1 + (size_t)bt * 3 + 0] = a0;
    dout[1 + (size_t)bt * 3 + 1] = a1;
    dout[1 + (size_t)bt * 3 + 2] = a2;
}

// ---------------- CRF NLL: log-semiring parallel scan ----------------
__device__ __forceinline__ float sel3(int i, float a, float b, float c) {
    return i == 0 ? a : (i == 1 ? b : c);
}
__device__ __forceinline__ float lse3(float a, float b, float c) {
    float m = fmaxf(a, fmaxf(b, c));
    float s = exp2f((a - m) * 1.44269504f) + exp2f((b - m) * 1.44269504f) + exp2f((c - m) * 1.44269504f);
    return m + log2f(s) * 0.69314718f;
}

__global__ __launch_bounds__(64) void crf_kernel(
    const int* __restrict__ tags,
    const float* __restrict__ start, const float* __restrict__ end,
    const float* __restrict__ trans, float* __restrict__ dout)
{
    const int b = blockIdx.x;
    const int th = threadIdx.x;
    const float* em = dout + 1 + (size_t)b * TT * 3;
    const int* tg = tags + (size_t)b * TT;

    float tr[3][3];
#pragma unroll
    for (int i = 0; i < 3; i++)
#pragma unroll
        for (int j = 0; j < 3; j++) tr[i][j] = trans[i * 3 + j];

    float P[3][3];
#pragma unroll
    for (int i = 0; i < 3; i++)
#pragma unroll
        for (int j = 0; j < 3; j++) P[i][j] = (i == j) ? 0.f : -1e30f;

    const int t0 = 1 + 16 * th;
    float numpart = 0.f;
    int tprev = tg[t0 - 1];

    for (int d = 0; d < 16; d++) {
        const int t = t0 + d;
        if (t < TT) {
            const float e0 = em[3 * t + 0], e1 = em[3 * t + 1], e2 = em[3 * t + 2];
            float N[3][3];
#pragma unroll
            for (int i = 0; i < 3; i++) {
                N[i][0] = lse3(P[i][0] + tr[0][0], P[i][1] + tr[1][0], P[i][2] + tr[2][0]) + e0;
                N[i][1] = lse3(P[i][0] + tr[0][1], P[i][1] + tr[1][1], P[i][2] + tr[2][1]) + e1;
                N[i][2] = lse3(P[i][0] + tr[0][2], P[i][1] + tr[1][2], P[i][2] + tr[2][2]) + e2;
            }
#pragma unroll
            for (int i = 0; i < 3; i++)
#pragma unroll
                for (int j = 0; j < 3; j++) P[i][j] = N[i][j];
            const int tc = tg[t];
            numpart += sel3(tc, e0, e1, e2) + sel3(tprev,
                         sel3(tc, tr[0][0], tr[0][1], tr[0][2]),
                         sel3(tc, tr[1][0], tr[1][1], tr[1][2]),
                         sel3(tc, tr[2][0], tr[2][1], tr[2][2]));
            tprev = tc;
        }
    }

#pragma unroll
    for (int off = 1; off < 64; off <<= 1) {
        float Q[3][3];
#pragma unroll
        for (int i = 0; i < 3; i++)
#pragma unroll
            for (int j = 0; j < 3; j++) Q[i][j] = __shfl_xor(P[i][j], off, 64);
        const bool hi = (th & off) != 0;
        float L[3][3], R[3][3];
#pragma unroll
        for (int i = 0; i < 3; i++)
#pragma unroll
            for (int j = 0; j < 3; j++) {
                L[i][j] = hi ? Q[i][j] : P[i][j];
                R[i][j] = hi ? P[i][j] : Q[i][j];
            }
#pragma unroll
        for (int i = 0; i < 3; i++)
#pragma unroll
            for (int j = 0; j < 3; j++)
                P[i][j] = lse3(L[i][0] + R[0][j], L[i][1] + R[1][j], L[i][2] + R[2][j]);
        numpart += __shfl_xor(numpart, off, 64);
    }

    if (th == 0) {
        const int tg0 = tg[0], tgL = tg[TT - 1];
        const float a0 = start[0] + em[0], a1 = start[1] + em[1], a2 = start[2] + em[2];
        const float f0 = lse3(a0 + P[0][0], a1 + P[1][0], a2 + P[2][0]);
        const float f1 = lse3(a0 + P[0][1], a1 + P[1][1], a2 + P[2][1]);
        const float f2 = lse3(a0 + P[0][2], a1 + P[1][2], a2 + P[2][2]);
        const float logZ = lse3(f0 + end[0], f1 + end[1], f2 + end[2]);
        const float num = sel3(tg0, start[0], start[1], start[2]) +
                          sel3(tg0, em[0], em[1], em[2]) + numpart +
                          sel3(tgL, end[0], end[1], end[2]);
        atomicAdd(&dout[0], (logZ - num) * (1.0f / (float)BB));
    }
}

// ---------------- launch ----------------
extern "C" void kernel_launch(void* const* d_in, const int* in_sizes, int n_in,
                              void* d_out, int out_size, void* d_ws, size_t ws_size,
                              hipStream_t stream) {
    const float* x        = (const float*)d_in[0];
    const int*   tags     = (const int*)d_in[1];
    const float* w_ih_l0  = (const float*)d_in[2];
    const float* w_hh_l0  = (const float*)d_in[3];
    const float* b_ih_l0  = (const float*)d_in[4];
    const float* b_hh_l0  = (const float*)d_in[5];
    const float* w_ih_l0r = (const float*)d_in[6];
    const float* w_hh_l0r = (const float*)d_in[7];
    const float* b_ih_l0r = (const float*)d_in[8];
    const float* b_hh_l0r = (const float*)d_in[9];
    const float* w_ih_l1  = (const float*)d_in[10];
    const float* w_hh_l1  = (const float*)d_in[11];
    const float* b_ih_l1  = (const float*)d_in[12];
    const float* b_hh_l1  = (const float*)d_in[13];
    const float* w_ih_l1r = (const float*)d_in[14];
    const float* w_hh_l1r = (const float*)d_in[15];
    const float* b_ih_l1r = (const float*)d_in[16];
    const float* b_hh_l1r = (const float*)d_in[17];
    const float* fc_w     = (const float*)d_in[18];
    const float* fc_b     = (const float*)d_in[19];
    const float* crf_start= (const float*)d_in[20];
    const float* crf_end  = (const float*)d_in[21];
    const float* crf_trans= (const float*)d_in[22];
    float* dout = (float*)d_out;

    uint8_t* ws = (uint8_t*)d_ws;
    unsigned short* xb   = (unsigned short*)(ws + 0);          // 33.5 MB, reused as out1 later
    unsigned short* out1 = xb;
    unsigned short* out0 = (unsigned short*)(ws + 33554432);   // 33.5 MB
    unsigned short* Gf   = (unsigned short*)(ws + 67108864);   // 67 MB
    unsigned short* Gr   = (unsigned short*)(ws + 134217728);  // 67 MB
    unsigned short* wb0  = (unsigned short*)(ws + 201326592);  // 4 x 256 KB
    unsigned short* wb0r = wb0 + 131072;
    unsigned short* wb1  = wb0 + 262144;
    unsigned short* wb1r = wb0 + 393216;

    // 1. convert x and the 4 w_ih matrices to bf16
    cvt4_kernel<<<dim3((16777216 / 4 + 255) / 256), dim3(256), 0, stream>>>(x, xb, 16777216 / 4);
    cvt4_kernel<<<dim3(128), dim3(256), 0, stream>>>(w_ih_l0,  wb0,  131072 / 4);
    cvt4_kernel<<<dim3(128), dim3(256), 0, stream>>>(w_ih_l0r, wb0r, 131072 / 4);
    cvt4_kernel<<<dim3(128), dim3(256), 0, stream>>>(w_ih_l1,  wb1,  131072 / 4);
    cvt4_kernel<<<dim3(128), dim3(256), 0, stream>>>(w_ih_l1r, wb1r, 131072 / 4);

    // 2. layer 0: input projection + MFMA scan
    gemm_ih<<<dim3(512, 4, 2), dim3(256), 0, stream>>>(
        xb, wb0, wb0r, b_ih_l0, b_hh_l0, b_ih_l0r, b_hh_l0r, Gf, Gr);
    lstm_scan_mfma<<<dim3(64, 2), dim3(512), 0, stream>>>(Gf, Gr, w_hh_l0, w_hh_l0r, out0);

    // 3. layer 1: input projection (reusing G buffers) + MFMA scan
    gemm_ih<<<dim3(512, 4, 2), dim3(256), 0, stream>>>(
        out0, wb1, wb1r, b_ih_l1, b_hh_l1, b_ih_l1r, b_hh_l1r, Gf, Gr);
    lstm_scan_mfma<<<dim3(64, 2), dim3(512), 0, stream>>>(Gf, Gr, w_hh_l1, w_hh_l1r, out1);

    // 4. emissions (also zeroes dout[0] for the CRF atomics)
    emis_kernel<<<dim3(256), dim3(256), 0, stream>>>(out1, fc_w, fc_b, dout);

    // 5. CRF NLL -> dout[0] (parallel scan, one block per batch)
    crf_kernel<<<dim3(64), dim3(64), 0, stream>>>(tags, crf_start, crf_end, crf_trans, dout);
}

// Round 8
// 1137.650 us; speedup vs baseline: 2.3582x; 1.0270x over previous
//
#include <hip/hip_runtime.h>
#include <cstdint>

// Problem constants
#define BB 64
#define TT 1024
#define DD 256
#define HH 128
#define G4 512   // 4*H
#define NTAG 3
#define PS 8388608   // plane stride: 65536 rows * 128 shorts (per-gate G plane)

typedef __attribute__((ext_vector_type(8))) short bf16x8;
typedef __attribute__((ext_vector_type(4))) float f32x4;
typedef __attribute__((ext_vector_type(4))) int i32x4;

__device__ __forceinline__ unsigned short f2bf(float f) {
    uint32_t u = __builtin_bit_cast(uint32_t, f);
    uint32_t r = (u + 0x7FFFu + ((u >> 16) & 1u)) >> 16;
    return (unsigned short)r;
}
__device__ __forceinline__ float bf2f(unsigned short s) {
    uint32_t u = ((uint32_t)s) << 16;
    return __builtin_bit_cast(float, u);
}
// raw HW transcendentals: v_exp_f32 / v_rcp_f32
__device__ __forceinline__ float sigm(float x) {
    return __builtin_amdgcn_rcpf(1.f + __builtin_amdgcn_exp2f(x * -1.44269504f));
}
__device__ __forceinline__ float tanh_f(float x) {
    return 1.f - 2.f * __builtin_amdgcn_rcpf(1.f + __builtin_amdgcn_exp2f(x * 2.88539008f));
}

// LDS-only barrier (no vmem drain) — scan kernel only.
__device__ __forceinline__ void block_sync_lds() {
    __builtin_amdgcn_s_waitcnt(0xC07F);
    __builtin_amdgcn_s_barrier();
}

// async global->LDS, 16B per lane; lds base must be wave-uniform (dest = base + lane*16)
#define ASYNC16(gp, lp) \
    __builtin_amdgcn_global_load_lds((const __attribute__((address_space(1))) unsigned int*)(gp), \
                                     (__attribute__((address_space(3))) unsigned int*)(lp), 16, 0, 0)

// ---------------- fp32 -> bf16 conversion (vectorized x4) ----------------
__global__ void cvt4_kernel(const float* __restrict__ in, unsigned short* __restrict__ out, int n4) {
    int idx = blockIdx.x * blockDim.x + threadIdx.x;
    if (idx < n4) {
        float4 v = ((const float4*)in)[idx];
        ushort4 o;
        o.x = f2bf(v.x); o.y = f2bf(v.y); o.z = f2bf(v.z); o.w = f2bf(v.w);
        ((ushort4*)out)[idx] = o;
    }
}

// ---------------- input-projection GEMM (LDS-staged, transposed-tile epilogue) ----------------
// G = A @ W^T + b_ih + b_hh.  A: [65536,256] bf16. W: [512,256] bf16 (N,K).
// G layout: per-gate planes [gate][row][hcol] (row = 128 shorts = 256B = 1 line).
// grid (512, 4, 2): x = 128-row M tile, y = gate, z = dir. 256 thr = 4 waves (2x2).
// Main loop: BK=64, 4 staged iters via global_load_lds w16. Epilogue: operand-SWAPPED
// MFMA (mfma(b,a)) yields G^T tiles -> each thread holds 4 consecutive G cols ->
// ushort4 (8B) contiguous stores, 4x fewer insts than 2B scatters.
__global__ __launch_bounds__(256) void gemm_ih(
    const unsigned short* __restrict__ A,
    const unsigned short* __restrict__ W0, const unsigned short* __restrict__ W1,
    const float* __restrict__ bih0, const float* __restrict__ bhh0,
    const float* __restrict__ bih1, const float* __restrict__ bhh1,
    unsigned short* __restrict__ G0, unsigned short* __restrict__ G1)
{
    const int dir = blockIdx.z;
    const unsigned short* W = dir ? W1 : W0;
    const float* bih = dir ? bih1 : bih0;
    const float* bhh = dir ? bhh1 : bhh0;
    unsigned short* G = dir ? G1 : G0;

    const int gate = blockIdx.y;
    const int m0 = blockIdx.x * 128;

    const int tid = threadIdx.x;
    const int wv = tid >> 6;
    const int lane = tid & 63;
    const int m16 = lane & 15;
    const int quad = lane >> 4;
    const int wave_m = wv & 1;
    const int wave_n = wv >> 1;

    __shared__ __align__(16) unsigned short As[128 * 64];
    __shared__ __align__(16) unsigned short Bs[128 * 64];

    f32x4 acc[4][4];
#pragma unroll
    for (int i = 0; i < 4; i++)
#pragma unroll
        for (int j = 0; j < 4; j++) acc[i][j] = (f32x4){0.f, 0.f, 0.f, 0.f};

    const int lrow = lane >> 3;          // 0..7: row within 8-row segment
    const int lcol = (lane & 7) * 8;     // k element offset (8 bf16 = 16B)

    for (int kt = 0; kt < 4; kt++) {
#pragma unroll
        for (int it = 0; it < 4; it++) {
            const int seg = wv * 4 + it;
            const int row = seg * 8 + lrow;
            ASYNC16(A + (size_t)(m0 + row) * DD + kt * 64 + lcol, As + seg * 512);
            ASYNC16(W + (size_t)(gate * 128 + row) * DD + kt * 64 + lcol, Bs + seg * 512);
        }
        __syncthreads();   // drains vmcnt -> staged data visible

#pragma unroll
        for (int kk = 0; kk < 2; kk++) {
            bf16x8 a[4], b[4];
#pragma unroll
            for (int i = 0; i < 4; i++) {
                const int row = wave_m * 64 + i * 16 + m16;
                a[i] = __builtin_bit_cast(bf16x8, *(const uint4*)&As[row * 64 + kk * 32 + quad * 8]);
            }
#pragma unroll
            for (int j = 0; j < 4; j++) {
                const int row = wave_n * 64 + j * 16 + m16;
                b[j] = __builtin_bit_cast(bf16x8, *(const uint4*)&Bs[row * 64 + kk * 32 + quad * 8]);
            }
            // operand swap: D = W_tile * A_tile^T = G^T tile
            //   C col (lane&15) = G row; C rows (quad*4+r) = G cols (consecutive!)
#pragma unroll
            for (int i = 0; i < 4; i++)
#pragma unroll
                for (int j = 0; j < 4; j++)
                    acc[i][j] = __builtin_amdgcn_mfma_f32_16x16x32_bf16(b[j], a[i], acc[i][j], 0, 0, 0);
        }
        __syncthreads();   // tile consumed; safe to restage
    }

    // epilogue: bias + contiguous ushort4 stores into this gate's plane
    unsigned short* Gp = G + (size_t)gate * PS;
    float bias[4][4];
#pragma unroll
    for (int j = 0; j < 4; j++)
#pragma unroll
        for (int r = 0; r < 4; r++) {
            const int n = gate * 128 + wave_n * 64 + j * 16 + quad * 4 + r;
            bias[j][r] = bih[n] + bhh[n];
        }
#pragma unroll
    for (int i = 0; i < 4; i++) {
        const int row = m0 + wave_m * 64 + i * 16 + m16;     // G row (from C col)
#pragma unroll
        for (int j = 0; j < 4; j++) {
            const int colbase = wave_n * 64 + j * 16 + quad * 4;  // G col (from C rows)
            ushort4 v;
            v.x = f2bf(acc[i][j][0] + bias[j][0]);
            v.y = f2bf(acc[i][j][1] + bias[j][1]);
            v.z = f2bf(acc[i][j][2] + bias[j][2]);
            v.w = f2bf(acc[i][j][3] + bias[j][3]);
            *(ushort4*)(Gp + (size_t)row * 128 + colbase) = v;
        }
    }
}

// ---------------- MFMA LSTM recurrent scan (i8 recurrence) ----------------
// grid (64, 2). 512 threads = 8 waves; wave wv owns hcols [16wv,16wv+16) for all 4 gates.
// w_hh quantized i8 scale 1024; h i8 scale 127; v_mfma_i32_16x16x64_i8, K=128 in 2 inst.
// Gates in acc regs; h (i8) double-buffered in LDS (broadcast reads); G preacts loaded
// from 4 per-gate planes, prefetched 4 steps ahead; LDS-only barrier.
__global__ __launch_bounds__(512, 2) void lstm_scan_mfma(
    const unsigned short* __restrict__ Gf, const unsigned short* __restrict__ Gr,
    const float* __restrict__ whh_f, const float* __restrict__ whh_r,
    unsigned short* __restrict__ out)
{
    const int b = blockIdx.x;
    const int dir = blockIdx.y;
    const unsigned short* G = dir ? Gr : Gf;
    const float* W = dir ? whh_r : whh_f;

    const int tid = threadIdx.x;
    const int wv = tid >> 6;
    const int lane = tid & 63;
    const int n16 = lane & 15;
    const int quad = lane >> 4;

    __shared__ __align__(16) signed char h8[2][HH];

    i32x4 bfrag[4][2];
#pragma unroll
    for (int p = 0; p < 4; p++) {
        const int n = 128 * p + wv * 16 + n16;
        const float* Wr = W + (size_t)n * HH;
#pragma unroll
        for (int kc = 0; kc < 2; kc++) {
            union { signed char c[16]; i32x4 v; } u;
#pragma unroll
            for (int j = 0; j < 16; j++) {
                float w = Wr[kc * 64 + quad * 16 + j] * 1024.f;
                int q = (int)rintf(w);
                q = q > 127 ? 127 : (q < -127 ? -127 : q);
                u.c[j] = (signed char)q;
            }
            bfrag[p][kc] = u.v;
        }
    }

    if (tid < HH) h8[0][tid] = 0;

    const bool dense = (quad == 0);
    const int hcol = wv * 16 + n16;
    float c = 0.f;
    const float INV = 1.f / 130048.f;   // 1/(1024*127)

    // per-lane G base within plane 0; gates at +p*PS
    const unsigned short* gbL = G + (size_t)b * TT * 128 + hcol;

    ushort4 gq[4];
#pragma unroll
    for (int d = 0; d < 4; d++) {
        const int t = dir ? (TT - 1 - d) : d;
        const unsigned short* gp = gbL + (size_t)t * 128;
        gq[d].x = gp[0];
        gq[d].y = gp[PS];
        gq[d].z = gp[2 * PS];
        gq[d].w = gp[3 * PS];
    }
    block_sync_lds();

    for (int sb = 0; sb < TT; sb += 4) {
#pragma unroll
        for (int d = 0; d < 4; d++) {
            const int s = sb + d;
            const int t = dir ? (TT - 1 - s) : s;
            const int buf = s & 1;

            i32x4 af[2];
#pragma unroll
            for (int kc = 0; kc < 2; kc++)
                af[kc] = __builtin_bit_cast(i32x4, *(const uint4*)&h8[buf][kc * 64 + quad * 16]);

            i32x4 acc[4];
#pragma unroll
            for (int p = 0; p < 4; p++) {
                i32x4 a = {0, 0, 0, 0};
                a = __builtin_amdgcn_mfma_i32_16x16x64_i8(af[0], bfrag[p][0], a, 0, 0, 0);
                a = __builtin_amdgcn_mfma_i32_16x16x64_i8(af[1], bfrag[p][1], a, 0, 0, 0);
                acc[p] = a;
            }

            if (dense) {
                const float gi = (float)acc[0][0] * INV + bf2f(gq[d].x);
                const float gf = (float)acc[1][0] * INV + bf2f(gq[d].y);
                const float gg = (float)acc[2][0] * INV + bf2f(gq[d].z);
                const float go = (float)acc[3][0] * INV + bf2f(gq[d].w);
                const float ig = sigm(gi);
                const float fg = sigm(gf);
                const float gt = tanh_f(gg);
                const float og = sigm(go);
                c = fg * c + ig * gt;
                const float h = og * tanh_f(c);
                h8[buf ^ 1][hcol] = (signed char)(int)rintf(h * 127.f);
                out[((size_t)b * TT + t) * (2 * HH) + dir * HH + hcol] = f2bf(h);
            }

            {
                int sn = s + 4;
                int tn = dir ? (TT - 1 - sn) : sn;
                tn = tn < 0 ? 0 : (tn > TT - 1 ? TT - 1 : tn);
                const unsigned short* gp = gbL + (size_t)tn * 128;
                gq[d].x = gp[0];
                gq[d].y = gp[PS];
                gq[d].z = gp[2 * PS];
                gq[d].w = gp[3 * PS];
            }
            block_sync_lds();
        }
    }
}

// ---------------- emissions: out1 [65536,256] bf16 @ fc_w^T [3,256] + fc_b ----------------
__global__ __launch_bounds__(256) void emis_kernel(
    const unsigned short* __restrict__ out1,
    const float* __restrict__ fcw, const float* __restrict__ fcb,
    float* __restrict__ dout)
{
    if (blockIdx.x == 0 && threadIdx.x == 0) dout[0] = 0.f; // init for CRF atomics

    __shared__ float wsm[NTAG * 256];
    for (int i = threadIdx.x; i < NTAG * 256; i += 256) wsm[i] = fcw[i];
    __syncthreads();

    const int bt = blockIdx.x * 256 + threadIdx.x;
    float a0 = fcb[0], a1 = fcb[1], a2 = fcb[2];
    const uint4* row = (const uint4*)(out1 + (size_t)bt * 256);
#pragma unroll 4
    for (int k8 = 0; k8 < 32; k8++) {
        uint4 u = row[k8];
        const int kb = k8 * 8;
        uint32_t p[4] = {u.x, u.y, u.z, u.w};
#pragma unroll
        for (int e = 0; e < 4; e++) {
            float flo = __builtin_bit_cast(float, p[e] << 16);
            float fhi = __builtin_bit_cast(float, p[e] & 0xFFFF0000u);
            const int k = kb + 2 * e;
            a0 = fmaf(flo, wsm[0 * 256 + k], a0);
            a1 = fmaf(flo, wsm[1 * 256 + k], a1);
            a2 = fmaf(flo, wsm[2 * 256 + k], a2);
            a0 = fmaf(fhi, wsm[0 * 256 + k + 1], a0);
            a1 = fmaf(fhi, wsm[1 * 256 + k + 1], a1);
            a2 = fmaf(fhi, wsm[2 * 256 + k + 1], a2);
        }
    }
    dout[1 + (size_t)bt * 3 + 0] = a0;
    dout[1 + (size_t)bt * 3 + 1] = a1;
    dout[1 + (size_t)bt * 3 + 2] = a2;
}

// ---------------- CRF NLL: log-semiring parallel scan ----------------
__device__ __forceinline__ float sel3(int i, float a, float b, float c) {
    return i == 0 ? a : (i == 1 ? b : c);
}
__device__ __forceinline__ float lse3(float a, float b, float c) {
    float m = fmaxf(a, fmaxf(b, c));
    float s = exp2f((a - m) * 1.44269504f) + exp2f((b - m) * 1.44269504f) + exp2f((c - m) * 1.44269504f);
    return m + log2f(s) * 0.69314718f;
}

__global__ __launch_bounds__(64) void crf_kernel(
    const int* __restrict__ tags,
    const float* __restrict__ start, const float* __restrict__ end,
    const float* __restrict__ trans, float* __restrict__ dout)
{
    const int b = blockIdx.x;
    const int th = threadIdx.x;
    const float* em = dout + 1 + (size_t)b * TT * 3;
    const int* tg = tags + (size_t)b * TT;

    float tr[3][3];
#pragma unroll
    for (int i = 0; i < 3; i++)
#pragma unroll
        for (int j = 0; j < 3; j++) tr[i][j] = trans[i * 3 + j];

    float P[3][3];
#pragma unroll
    for (int i = 0; i < 3; i++)
#pragma unroll
        for (int j = 0; j < 3; j++) P[i][j] = (i == j) ? 0.f : -1e30f;

    const int t0 = 1 + 16 * th;
    float numpart = 0.f;
    int tprev = tg[t0 - 1];

    for (int d = 0; d < 16; d++) {
        const int t = t0 + d;
        if (t < TT) {
            const float e0 = em[3 * t + 0], e1 = em[3 * t + 1], e2 = em[3 * t + 2];
            float N[3][3];
#pragma unroll
            for (int i = 0; i < 3; i++) {
                N[i][0] = lse3(P[i][0] + tr[0][0], P[i][1] + tr[1][0], P[i][2] + tr[2][0]) + e0;
                N[i][1] = lse3(P[i][0] + tr[0][1], P[i][1] + tr[1][1], P[i][2] + tr[2][1]) + e1;
                N[i][2] = lse3(P[i][0] + tr[0][2], P[i][1] + tr[1][2], P[i][2] + tr[2][2]) + e2;
            }
#pragma unroll
            for (int i = 0; i < 3; i++)
#pragma unroll
                for (int j = 0; j < 3; j++) P[i][j] = N[i][j];
            const int tc = tg[t];
            numpart += sel3(tc, e0, e1, e2) + sel3(tprev,
                         sel3(tc, tr[0][0], tr[0][1], tr[0][2]),
                         sel3(tc, tr[1][0], tr[1][1], tr[1][2]),
                         sel3(tc, tr[2][0], tr[2][1], tr[2][2]));
            tprev = tc;
        }
    }

#pragma unroll
    for (int off = 1; off < 64; off <<= 1) {
        float Q[3][3];
#pragma unroll
        for (int i = 0; i < 3; i++)
#pragma unroll
            for (int j = 0; j < 3; j++) Q[i][j] = __shfl_xor(P[i][j], off, 64);
        const bool hi = (th & off) != 0;
        float L[3][3], R[3][3];
#pragma unroll
        for (int i = 0; i < 3; i++)
#pragma unroll
            for (int j = 0; j < 3; j++) {
                L[i][j] = hi ? Q[i][j] : P[i][j];
                R[i][j] = hi ? P[i][j] : Q[i][j];
            }
#pragma unroll
        for (int i = 0; i < 3; i++)
#pragma unroll
            for (int j = 0; j < 3; j++)
                P[i][j] = lse3(L[i][0] + R[0][j], L[i][1] + R[1][j], L[i][2] + R[2][j]);
        numpart += __shfl_xor(numpart, off, 64);
    }

    if (th == 0) {
        const int tg0 = tg[0], tgL = tg[TT - 1];
        const float a0 = start[0] + em[0], a1 = start[1] + em[1], a2 = start[2] + em[2];
        const float f0 = lse3(a0 + P[0][0], a1 + P[1][0], a2 + P[2][0]);
        const float f1 = lse3(a0 + P[0][1], a1 + P[1][1], a2 + P[2][1]);
        const float f2 = lse3(a0 + P[0][2], a1 + P[1][2], a2 + P[2][2]);
        const float logZ = lse3(f0 + end[0], f1 + end[1], f2 + end[2]);
        const float num = sel3(tg0, start[0], start[1], start[2]) +
                          sel3(tg0, em[0], em[1], em[2]) + numpart +
                          sel3(tgL, end[0], end[1], end[2]);
        atomicAdd(&dout[0], (logZ - num) * (1.0f / (float)BB));
    }
}

// ---------------- launch ----------------
extern "C" void kernel_launch(void* const* d_in, const int* in_sizes, int n_in,
                              void* d_out, int out_size, void* d_ws, size_t ws_size,
                              hipStream_t stream) {
    const float* x        = (const float*)d_in[0];
    const int*   tags     = (const int*)d_in[1];
    const float* w_ih_l0  = (const float*)d_in[2];
    const float* w_hh_l0  = (const float*)d_in[3];
    const float* b_ih_l0  = (const float*)d_in[4];
    const float* b_hh_l0  = (const float*)d_in[5];
    const float* w_ih_l0r = (const float*)d_in[6];
    const float* w_hh_l0r = (const float*)d_in[7];
    const float* b_ih_l0r = (const float*)d_in[8];
    const float* b_hh_l0r = (const float*)d_in[9];
    const float* w_ih_l1  = (const float*)d_in[10];
    const float* w_hh_l1  = (const float*)d_in[11];
    const float* b_ih_l1  = (const float*)d_in[12];
    const float* b_hh_l1  = (const float*)d_in[13];
    const float* w_ih_l1r = (const float*)d_in[14];
    const float* w_hh_l1r = (const float*)d_in[15];
    const float* b_ih_l1r = (const float*)d_in[16];
    const float* b_hh_l1r = (const float*)d_in[17];
    const float* fc_w     = (const float*)d_in[18];
    const float* fc_b     = (const float*)d_in[19];
    const float* crf_start= (const float*)d_in[20];
    const float* crf_end  = (const float*)d_in[21];
    const float* crf_trans= (const float*)d_in[22];
    float* dout = (float*)d_out;

    uint8_t* ws = (uint8_t*)d_ws;
    unsigned short* xb   = (unsigned short*)(ws + 0);          // 33.5 MB, reused as out1 later
    unsigned short* out1 = xb;
    unsigned short* out0 = (unsigned short*)(ws + 33554432);   // 33.5 MB
    unsigned short* Gf   = (unsigned short*)(ws + 67108864);   // 67 MB (4 planes of 16.75 MB)
    unsigned short* Gr   = (unsigned short*)(ws + 134217728);  // 67 MB
    unsigned short* wb0  = (unsigned short*)(ws + 201326592);  // 4 x 256 KB
    unsigned short* wb0r = wb0 + 131072;
    unsigned short* wb1  = wb0 + 262144;
    unsigned short* wb1r = wb0 + 393216;

    // 1. convert x and the 4 w_ih matrices to bf16
    cvt4_kernel<<<dim3((16777216 / 4 + 255) / 256), dim3(256), 0, stream>>>(x, xb, 16777216 / 4);
    cvt4_kernel<<<dim3(128), dim3(256), 0, stream>>>(w_ih_l0,  wb0,  131072 / 4);
    cvt4_kernel<<<dim3(128), dim3(256), 0, stream>>>(w_ih_l0r, wb0r, 131072 / 4);
    cvt4_kernel<<<dim3(128), dim3(256), 0, stream>>>(w_ih_l1,  wb1,  131072 / 4);
    cvt4_kernel<<<dim3(128), dim3(256), 0, stream>>>(w_ih_l1r, wb1r, 131072 / 4);

    // 2. layer 0: input projection + MFMA scan
    gemm_ih<<<dim3(512, 4, 2), dim3(256), 0, stream>>>(
        xb, wb0, wb0r, b_ih_l0, b_hh_l0, b_ih_l0r, b_hh_l0r, Gf, Gr);
    lstm_scan_mfma<<<dim3(64, 2), dim3(512), 0, stream>>>(Gf, Gr, w_hh_l0, w_hh_l0r, out0);

    // 3. layer 1: input projection (reusing G buffers) + MFMA scan
    gemm_ih<<<dim3(512, 4, 2), dim3(256), 0, stream>>>(
        out0, wb1, wb1r, b_ih_l1, b_hh_l1, b_ih_l1r, b_hh_l1r, Gf, Gr);
    lstm_scan_mfma<<<dim3(64, 2), dim3(512), 0, stream>>>(Gf, Gr, w_hh_l1, w_hh_l1r, out1);

    // 4. emissions (also zeroes dout[0] for the CRF atomics)
    emis_kernel<<<dim3(256), dim3(256), 0, stream>>>(out1, fc_w, fc_b, dout);

    // 5. CRF NLL -> dout[0] (parallel scan, one block per batch)
    crf_kernel<<<dim3(64), dim3(64), 0, stream>>>(tags, crf_start, crf_end, crf_trans, dout);
}